// Round 2
// baseline (1307.248 us; speedup 1.0000x reference)
//
#include <hip/hip_runtime.h>
#include <hip/hip_bf16.h>

#define U_N 100000
#define I_N 50000
#define E_N 2000000
#define R_N 5
#define C_N (I_N*R_N)   // 250000 (item,rating) combos

typedef __hip_bfloat16 bf16_t;
typedef unsigned short u16;

__device__ __forceinline__ float blo(unsigned u){ return __uint_as_float(u<<16); }
__device__ __forceinline__ float bhi(unsigned u){ return __uint_as_float(u & 0xffff0000u); }

// load 64 f32 (one row, 256B) into regs
__device__ __forceinline__ void load64_f32(const float4* p, float* x){
#pragma unroll
  for(int q=0;q<16;q++){
    float4 v = p[q];
    x[q*4+0]=v.x; x[q*4+1]=v.y; x[q*4+2]=v.z; x[q*4+3]=v.w;
  }
}

// load 64 bf16 (one row, 128B) into f32 regs
__device__ __forceinline__ void load64_bf16(const uint4* p, float* x){
#pragma unroll
  for(int i=0;i<8;i++){
    uint4 v = p[i];
    x[i*8+0]=blo(v.x); x[i*8+1]=bhi(v.x);
    x[i*8+2]=blo(v.y); x[i*8+3]=bhi(v.y);
    x[i*8+4]=blo(v.z); x[i*8+5]=bhi(v.z);
    x[i*8+6]=blo(v.w); x[i*8+7]=bhi(v.w);
  }
}

// stage rows [koff..koff+63] of W[K][64] (f32) transposed into LDS: Wt[d*64+k]
__device__ __forceinline__ void stage_wt(const float* w, int koff, float* Wt, int tid, int nth){
  for(int idx=tid; idx<4096; idx+=nth){
    int d = idx & 63, k = idx >> 6;
    Wt[d*64+k] = w[(size_t)(koff+k)*64 + d];
  }
}

// x[64] regs dot LDS row (broadcast reads, 4 independent FMA chains)
__device__ __forceinline__ float dot64(const float* Wrow, const float* x){
  const float4* wr = (const float4*)Wrow;
  float a0=0.f,a1=0.f,a2=0.f,a3=0.f;
#pragma unroll
  for(int q=0;q<16;q++){
    float4 w = wr[q];
    a0 += x[q*4+0]*w.x;
    a1 += x[q*4+1]*w.y;
    a2 += x[q*4+2]*w.z;
    a3 += x[q*4+3]*w.w;
  }
  return (a0+a1)+(a2+a3);
}

__global__ __launch_bounds__(256) void k_zero(float* h, unsigned* segkey, float* segsum){
  int i = blockIdx.x*256 + threadIdx.x;
  if(i < U_N*64) h[i] = 0.f;
  if(i < U_N){ segkey[i] = 0u; segsum[i] = 0.f; }
}

// rating_part[r][d] = gv_b1[d] + sum_k rf[r][k] * gv_w1[64+k][d]
__global__ void k_ratpart(const float* __restrict__ rf, const float* __restrict__ w1,
                          const float* __restrict__ b1, float* __restrict__ out){
  int t = threadIdx.x; if(t >= R_N*64) return;
  int r = t>>6, d = t&63;
  float acc = b1[d];
  for(int k=0;k<64;k++) acc += rf[r*64 + k] * w1[(64+k)*64 + d];
  out[t] = acc;
}

// item_part[i][d] = sum_k item[i][k] * gv_w1[k][d]   (no bias, no act)
__global__ __launch_bounds__(256) void k_itempart(const float4* __restrict__ itemf,
                                                  const float* __restrict__ w1,
                                                  float* __restrict__ out){
  __shared__ float Wt[4096];
  stage_wt(w1, 0, Wt, threadIdx.x, 256);
  __syncthreads();
  int i = blockIdx.x*256 + threadIdx.x; if(i >= I_N) return;
  float x[64]; load64_f32(itemf + (size_t)i*16, x);
  float* orow = out + (size_t)i*64;
  for(int d=0; d<64; d++) orow[d] = dot64(&Wt[d*64], x);
}

// user_part[u][d] = att_b1[d] + sum_k user[u][k] * att_w1[64+k][d]  (bf16 out)
__global__ __launch_bounds__(256) void k_userpart(const float4* __restrict__ userf,
                                                  const float* __restrict__ a1w,
                                                  const float* __restrict__ a1b,
                                                  bf16_t* __restrict__ out){
  __shared__ float Wt[4096]; __shared__ float bs[64];
  stage_wt(a1w, 64, Wt, threadIdx.x, 256);
  if(threadIdx.x < 64) bs[threadIdx.x] = a1b[threadIdx.x];
  __syncthreads();
  int u = blockIdx.x*256 + threadIdx.x; if(u >= U_N) return;
  float x[64]; load64_f32(userf + (size_t)u*16, x);
  bf16_t* orow = out + (size_t)u*64;
  for(int d=0; d<64; d++) orow[d] = __float2bfloat16(dot64(&Wt[d*64], x) + bs[d]);
}

// per (item,rating) combo c=i*5+r:
//   h1 = relu(item_part[i] + rating_part[r])           (gv_b1 folded in rating_part)
//   x_ia = relu(h1 @ gv_w2 + gv_b2)        -> xia_t[c]  (f32)
//   xa1  = x_ia @ att_w1[0:64]             -> xa1_t[c]  (bf16)
__global__ __launch_bounds__(256) void k_combo(const float* __restrict__ item_part,
                                               const float* __restrict__ rating_part,
                                               const float* __restrict__ w2, const float* __restrict__ b2,
                                               const float* __restrict__ a1w,
                                               float* __restrict__ xia_t, bf16_t* __restrict__ xa1_t){
  __shared__ float W2t[4096]; __shared__ float A1t[4096]; __shared__ float b2s[64];
  stage_wt(w2, 0, W2t, threadIdx.x, 256);
  stage_wt(a1w, 0, A1t, threadIdx.x, 256);
  if(threadIdx.x < 64) b2s[threadIdx.x] = b2[threadIdx.x];
  __syncthreads();
  int c = blockIdx.x*256 + threadIdx.x; if(c >= C_N) return;
  int i = c/5, r = c - i*5;
  float x[64], y[64];
  const float4* ip = (const float4*)(item_part + (size_t)i*64);
  const float4* rp = (const float4*)(rating_part + (size_t)r*64);
#pragma unroll
  for(int q=0;q<16;q++){
    float4 a = ip[q], b = rp[q];
    x[q*4+0] = fmaxf(a.x+b.x, 0.f);
    x[q*4+1] = fmaxf(a.y+b.y, 0.f);
    x[q*4+2] = fmaxf(a.z+b.z, 0.f);
    x[q*4+3] = fmaxf(a.w+b.w, 0.f);
  }
  float* orow = xia_t + (size_t)c*64;
  for(int d=0; d<64; d++){
    float v = fmaxf(dot64(&W2t[d*64], x) + b2s[d], 0.f);
    y[d] = v;
    orow[d] = v;
  }
  bf16_t* orow2 = xa1_t + (size_t)c*64;
  for(int d=0; d<64; d++)
    orow2[d] = __float2bfloat16(dot64(&A1t[d*64], y));
}

// per edge: a1 = relu(xa1_t[c] + user_part[u]); a2 = relu(a1@att_w2 + att_b2); logit = a2.att_w3 + b3
__global__ __launch_bounds__(256) void k_edge(const int* __restrict__ rows, const int* __restrict__ cols,
                                              const int* __restrict__ rats,
                                              const uint4* __restrict__ xa1p, const uint4* __restrict__ userp,
                                              const float* __restrict__ a2w, const float* __restrict__ a2b,
                                              const float* __restrict__ a3w, const float* __restrict__ a3b,
                                              float* __restrict__ wlog){
  __shared__ float Wt[4096]; __shared__ float bs[64]; __shared__ float a3s[64];
  stage_wt(a2w, 0, Wt, threadIdx.x, 256);
  if(threadIdx.x < 64){ bs[threadIdx.x]=a2b[threadIdx.x]; a3s[threadIdx.x]=a3w[threadIdx.x]; }
  __syncthreads();
  int e = blockIdx.x*256 + threadIdx.x; if(e >= E_N) return;
  int it = rows[e], u = cols[e], r = rats[e];
  int c = it*5 + r;
  float x[64];
  load64_bf16(xa1p + (size_t)c*8, x);
  const uint4* up = userp + (size_t)u*8;
#pragma unroll
  for(int i=0;i<8;i++){
    uint4 v = up[i];
    x[i*8+0]+=blo(v.x); x[i*8+1]+=bhi(v.x);
    x[i*8+2]+=blo(v.y); x[i*8+3]+=bhi(v.y);
    x[i*8+4]+=blo(v.z); x[i*8+5]+=bhi(v.z);
    x[i*8+6]+=blo(v.w); x[i*8+7]+=bhi(v.w);
  }
#pragma unroll
  for(int k=0;k<64;k++) x[k] = fmaxf(x[k], 0.f);
  float wsum = a3b[0];
  for(int d=0; d<64; d++){
    float v = fmaxf(dot64(&Wt[d*64], x) + bs[d], 0.f);
    wsum += v * a3s[d];
  }
  wlog[e] = wsum;
}

// monotone-uint float max
__global__ __launch_bounds__(256) void k_segmax(const float* __restrict__ wlog,
                                                const int* __restrict__ cols,
                                                unsigned* __restrict__ segkey){
  int e = blockIdx.x*256 + threadIdx.x; if(e >= E_N) return;
  unsigned b = __float_as_uint(wlog[e]);
  unsigned key = (b & 0x80000000u) ? ~b : (b | 0x80000000u);
  atomicMax(segkey + cols[e], key);
}

__global__ __launch_bounds__(256) void k_expsum(const float* __restrict__ wlog,
                                                const int* __restrict__ cols,
                                                const unsigned* __restrict__ segkey,
                                                float* __restrict__ expv, float* __restrict__ segsum){
  int e = blockIdx.x*256 + threadIdx.x; if(e >= E_N) return;
  int u = cols[e];
  unsigned key = segkey[u];
  unsigned b = (key & 0x80000000u) ? (key ^ 0x80000000u) : ~key;
  float m = __uint_as_float(b);
  float ex = __expf(wlog[e] - m);
  expv[e] = ex;
  atomicAdd(segsum + u, ex);
}

// h[u][d] += x_ia[c][d] * (expv[e]/segsum[u]);  4 waves per block, lane pair = edge slot
__global__ __launch_bounds__(256) void k_scatter(const int* __restrict__ rows, const int* __restrict__ cols,
                                                 const int* __restrict__ rats,
                                                 const float* __restrict__ expv, const float* __restrict__ segsum,
                                                 const float* __restrict__ xia_t, float* __restrict__ h){
  long long t = (long long)blockIdx.x*256 + threadIdx.x;
  int e = (int)(t >> 6), d = (int)(t & 63);
  if(e >= E_N) return;
  int u = cols[e];
  float val = expv[e] / segsum[u];
  int c = rows[e]*5 + rats[e];
  float x = xia_t[(size_t)c*64 + d];
  atomicAdd(h + (size_t)u*64 + d, x*val);
}

// out[u][d] = h[u] . w_w[:,d] + w_b[d]
__global__ __launch_bounds__(256) void k_out(const float* __restrict__ h,
                                             const float* __restrict__ ww, const float* __restrict__ wb,
                                             float* __restrict__ out){
  __shared__ float Wt[4096]; __shared__ float bs[64];
  stage_wt(ww, 0, Wt, threadIdx.x, 256);
  if(threadIdx.x < 64) bs[threadIdx.x] = wb[threadIdx.x];
  __syncthreads();
  int u = blockIdx.x*256 + threadIdx.x; if(u >= U_N) return;
  float x[64];
  load64_f32((const float4*)(h + (size_t)u*64), x);
  float* orow = out + (size_t)u*64;
  for(int d=0; d<64; d++) orow[d] = dot64(&Wt[d*64], x) + bs[d];
}

extern "C" void kernel_launch(void* const* d_in, const int* in_sizes, int n_in,
                              void* d_out, int out_size, void* d_ws, size_t ws_size,
                              hipStream_t stream){
  (void)in_sizes; (void)n_in; (void)out_size; (void)ws_size;
  const float4* user_feat  = (const float4*)d_in[0];
  const float4* item_feat  = (const float4*)d_in[1];
  const float*  rating_feat= (const float*)d_in[2];
  const int*    rows       = (const int*)d_in[3];
  const int*    cols       = (const int*)d_in[4];
  const int*    rats       = (const int*)d_in[5];
  const float* gv_w1 = (const float*)d_in[6];
  const float* gv_b1 = (const float*)d_in[7];
  const float* gv_w2 = (const float*)d_in[8];
  const float* gv_b2 = (const float*)d_in[9];
  const float* att_w1= (const float*)d_in[10];
  const float* att_b1= (const float*)d_in[11];
  const float* att_w2= (const float*)d_in[12];
  const float* att_b2= (const float*)d_in[13];
  const float* att_w3= (const float*)d_in[14];
  const float* att_b3= (const float*)d_in[15];
  const float* w_w   = (const float*)d_in[16];
  const float* w_b   = (const float*)d_in[17];
  float* out = (float*)d_out;

  char* ws = (char*)d_ws; size_t off = 0;
  auto take = [&](size_t b)->char*{ char* p = ws + off; off = (off + b + 255) & ~(size_t)255; return p; };
  float*    h_acc      = (float*)   take((size_t)U_N*64*4);   // 25.6 MB
  float*    item_part  = (float*)   take((size_t)I_N*64*4);   // 12.8 MB
  bf16_t*   user_part  = (bf16_t*)  take((size_t)U_N*64*2);   // 12.8 MB
  float*    rating_part= (float*)   take((size_t)R_N*64*4);
  float*    xia_t      = (float*)   take((size_t)C_N*64*4);   // 64 MB
  bf16_t*   xa1_t      = (bf16_t*)  take((size_t)C_N*64*2);   // 32 MB
  float*    wlog       = (float*)   take((size_t)E_N*4);      // 8 MB
  float*    expv       = (float*)   take((size_t)E_N*4);      // 8 MB
  unsigned* segkey     = (unsigned*)take((size_t)U_N*4);
  float*    segsum     = (float*)   take((size_t)U_N*4);

  k_zero    <<<(U_N*64)/256, 256, 0, stream>>>(h_acc, segkey, segsum);
  k_ratpart <<<1, 320, 0, stream>>>(rating_feat, gv_w1, gv_b1, rating_part);
  k_itempart<<<(I_N+255)/256, 256, 0, stream>>>(item_feat, gv_w1, item_part);
  k_userpart<<<(U_N+255)/256, 256, 0, stream>>>(user_feat, att_w1, att_b1, user_part);
  k_combo   <<<(C_N+255)/256, 256, 0, stream>>>(item_part, rating_part, gv_w2, gv_b2, att_w1, xia_t, xa1_t);
  k_edge    <<<(E_N+255)/256, 256, 0, stream>>>(rows, cols, rats, (const uint4*)xa1_t, (const uint4*)user_part,
                                                att_w2, att_b2, att_w3, att_b3, wlog);
  k_segmax  <<<(E_N+255)/256, 256, 0, stream>>>(wlog, cols, segkey);
  k_expsum  <<<(E_N+255)/256, 256, 0, stream>>>(wlog, cols, segkey, expv, segsum);
  k_scatter <<<(int)(((size_t)E_N*64)/256), 256, 0, stream>>>(rows, cols, rats, expv, segsum, xia_t, h_acc);
  k_out     <<<(U_N+255)/256, 256, 0, stream>>>(h_acc, w_w, w_b, out);
}

// Round 3
// 1001.996 us; speedup vs baseline: 1.3046x; 1.3046x over previous
//
#include <hip/hip_runtime.h>
#include <hip/hip_bf16.h>

#define U_N 100000
#define I_N 50000
#define E_N 2000000
#define R_N 5
#define C_N (I_N*R_N)   // 250000 (item,rating) combos
#define NBLK_U 391      // ceil(100000/256); NBLK_U*256 = 100096

typedef __hip_bfloat16 bf16_t;
typedef unsigned short u16;

__device__ __forceinline__ float blo(unsigned u){ return __uint_as_float(u<<16); }
__device__ __forceinline__ float bhi(unsigned u){ return __uint_as_float(u & 0xffff0000u); }

__device__ __forceinline__ void load64_f32(const float4* p, float* x){
#pragma unroll
  for(int q=0;q<16;q++){
    float4 v = p[q];
    x[q*4+0]=v.x; x[q*4+1]=v.y; x[q*4+2]=v.z; x[q*4+3]=v.w;
  }
}

__device__ __forceinline__ void load64_bf16(const uint4* p, float* x){
#pragma unroll
  for(int i=0;i<8;i++){
    uint4 v = p[i];
    x[i*8+0]=blo(v.x); x[i*8+1]=bhi(v.x);
    x[i*8+2]=blo(v.y); x[i*8+3]=bhi(v.y);
    x[i*8+4]=blo(v.z); x[i*8+5]=bhi(v.z);
    x[i*8+6]=blo(v.w); x[i*8+7]=bhi(v.w);
  }
}

// stage rows [koff..koff+63] of W[K][64] transposed into LDS: Wt[d*64+k]
__device__ __forceinline__ void stage_wt(const float* w, int koff, float* Wt, int tid, int nth){
  for(int idx=tid; idx<4096; idx+=nth){
    int d = idx & 63, k = idx >> 6;
    Wt[d*64+k] = w[(size_t)(koff+k)*64 + d];
  }
}
// stage W[64][64] as-is (row-major) into LDS
__device__ __forceinline__ void stage_w(const float* w, float* Ws, int tid, int nth){
  for(int idx=tid; idx<4096; idx+=nth) Ws[idx] = w[idx];
}

// x[64] regs dot LDS row (broadcast reads, 4 independent FMA chains)
__device__ __forceinline__ float dot64(const float* Wrow, const float* x){
  const float4* wr = (const float4*)Wrow;
  float a0=0.f,a1=0.f,a2=0.f,a3=0.f;
#pragma unroll
  for(int q=0;q<16;q++){
    float4 w = wr[q];
    a0 += x[q*4+0]*w.x;
    a1 += x[q*4+1]*w.y;
    a2 += x[q*4+2]*w.z;
    a3 += x[q*4+3]*w.w;
  }
  return (a0+a1)+(a2+a3);
}

// ---------------- CSR build ----------------
__global__ __launch_bounds__(256) void k_zero(int* cnt, int* fill){
  int i = blockIdx.x*256 + threadIdx.x;
  if(i < U_N){ cnt[i]=0; fill[i]=0; }
}

__global__ __launch_bounds__(256) void k_count(const int* __restrict__ cols, int* __restrict__ cnt){
  int e = blockIdx.x*256 + threadIdx.x; if(e >= E_N) return;
  atomicAdd(cnt + cols[e], 1);
}

__global__ __launch_bounds__(256) void k_scanA(const int* __restrict__ cnt, int* __restrict__ start,
                                               int* __restrict__ bsum){
  __shared__ int s[256];
  int t = threadIdx.x, i = blockIdx.x*256 + t;
  int v = (i < U_N) ? cnt[i] : 0;
  s[t] = v; __syncthreads();
  for(int off=1; off<256; off<<=1){
    int x = (t>=off) ? s[t-off] : 0;
    __syncthreads();
    s[t] += x;
    __syncthreads();
  }
  start[i] = s[t] - v;            // exclusive within block
  if(t == 255) bsum[blockIdx.x] = s[255];
}

__global__ void k_scanB(int* bsum, int n){   // single block, in-place exclusive scan
  __shared__ int s[512];
  int t = threadIdx.x;
  int v = (t < n) ? bsum[t] : 0;
  s[t] = v; __syncthreads();
  for(int off=1; off<512; off<<=1){
    int x = (t>=off) ? s[t-off] : 0;
    __syncthreads();
    s[t] += x;
    __syncthreads();
  }
  if(t < n) bsum[t] = s[t] - v;
}

__global__ __launch_bounds__(256) void k_scanC(int* start, const int* __restrict__ bsum){
  int i = blockIdx.x*256 + threadIdx.x;
  start[i] += bsum[blockIdx.x];
}

__global__ __launch_bounds__(256) void k_place(const int* __restrict__ rows, const int* __restrict__ cols,
                                               const int* __restrict__ rats,
                                               const int* __restrict__ start, int* __restrict__ fill,
                                               int* __restrict__ u_s, int* __restrict__ c_s){
  int e = blockIdx.x*256 + threadIdx.x; if(e >= E_N) return;
  int u = cols[e];
  int pos = start[u] + atomicAdd(fill + u, 1);
  u_s[pos] = u;
  c_s[pos] = rows[e]*5 + rats[e];
}

// ---------------- dense precompute ----------------
__global__ void k_ratpart(const float* __restrict__ rf, const float* __restrict__ w1,
                          const float* __restrict__ b1, float* __restrict__ out){
  int t = threadIdx.x; if(t >= R_N*64) return;
  int r = t>>6, d = t&63;
  float acc = b1[d];
  for(int k=0;k<64;k++) acc += rf[r*64 + k] * w1[(64+k)*64 + d];
  out[t] = acc;
}

__global__ __launch_bounds__(256) void k_itempart(const float4* __restrict__ itemf,
                                                  const float* __restrict__ w1,
                                                  float* __restrict__ out){
  __shared__ float Wt[4096];
  stage_wt(w1, 0, Wt, threadIdx.x, 256);
  __syncthreads();
  int i = blockIdx.x*256 + threadIdx.x; if(i >= I_N) return;
  float x[64]; load64_f32(itemf + (size_t)i*16, x);
  float* orow = out + (size_t)i*64;
  for(int d=0; d<64; d++) orow[d] = dot64(&Wt[d*64], x);
}

__global__ __launch_bounds__(256) void k_userpart(const float4* __restrict__ userf,
                                                  const float* __restrict__ a1w,
                                                  const float* __restrict__ a1b,
                                                  bf16_t* __restrict__ out){
  __shared__ float Wt[4096]; __shared__ float bs[64];
  stage_wt(a1w, 64, Wt, threadIdx.x, 256);
  if(threadIdx.x < 64) bs[threadIdx.x] = a1b[threadIdx.x];
  __syncthreads();
  int u = blockIdx.x*256 + threadIdx.x; if(u >= U_N) return;
  float x[64]; load64_f32(userf + (size_t)u*16, x);
  bf16_t* orow = out + (size_t)u*64;
  for(int d=0; d<64; d++) orow[d] = __float2bfloat16(dot64(&Wt[d*64], x) + bs[d]);
}

// per (item,rating) combo: x_ia (bf16) and xa1 = x_ia @ att_w1_top (bf16)
__global__ __launch_bounds__(256) void k_combo(const float* __restrict__ item_part,
                                               const float* __restrict__ rating_part,
                                               const float* __restrict__ w2, const float* __restrict__ b2,
                                               const float* __restrict__ a1w,
                                               bf16_t* __restrict__ xia_t, bf16_t* __restrict__ xa1_t){
  __shared__ float W2t[4096]; __shared__ float A1t[4096]; __shared__ float b2s[64];
  stage_wt(w2, 0, W2t, threadIdx.x, 256);
  stage_wt(a1w, 0, A1t, threadIdx.x, 256);
  if(threadIdx.x < 64) b2s[threadIdx.x] = b2[threadIdx.x];
  __syncthreads();
  int c = blockIdx.x*256 + threadIdx.x; if(c >= C_N) return;
  int i = c/5, r = c - i*5;
  float x[64], y[64];
  const float4* ip = (const float4*)(item_part + (size_t)i*64);
  const float4* rp = (const float4*)(rating_part + (size_t)r*64);
#pragma unroll
  for(int q=0;q<16;q++){
    float4 a = ip[q], b = rp[q];
    x[q*4+0] = fmaxf(a.x+b.x, 0.f);
    x[q*4+1] = fmaxf(a.y+b.y, 0.f);
    x[q*4+2] = fmaxf(a.z+b.z, 0.f);
    x[q*4+3] = fmaxf(a.w+b.w, 0.f);
  }
  bf16_t* orow = xia_t + (size_t)c*64;
  for(int d=0; d<64; d++){
    float v = fmaxf(dot64(&W2t[d*64], x) + b2s[d], 0.f);
    y[d] = v;
    orow[d] = __float2bfloat16(v);
  }
  bf16_t* orow2 = xa1_t + (size_t)c*64;
  for(int d=0; d<64; d++)
    orow2[d] = __float2bfloat16(dot64(&A1t[d*64], y));
}

// per sorted edge slot: logit (sorted order -> user_part reads are segment-local, wlog write coalesced)
__global__ __launch_bounds__(256) void k_edge(const int* __restrict__ u_s, const int* __restrict__ c_s,
                                              const uint4* __restrict__ xa1p, const uint4* __restrict__ userp,
                                              const float* __restrict__ a2w, const float* __restrict__ a2b,
                                              const float* __restrict__ a3w, const float* __restrict__ a3b,
                                              float* __restrict__ wlog){
  __shared__ float Wt[4096]; __shared__ float bs[64]; __shared__ float a3s[64];
  stage_wt(a2w, 0, Wt, threadIdx.x, 256);
  if(threadIdx.x < 64){ bs[threadIdx.x]=a2b[threadIdx.x]; a3s[threadIdx.x]=a3w[threadIdx.x]; }
  __syncthreads();
  int e = blockIdx.x*256 + threadIdx.x; if(e >= E_N) return;
  int u = u_s[e], c = c_s[e];
  float x[64];
  load64_bf16(xa1p + (size_t)c*8, x);
  const uint4* up = userp + (size_t)u*8;
#pragma unroll
  for(int i=0;i<8;i++){
    uint4 v = up[i];
    x[i*8+0]+=blo(v.x); x[i*8+1]+=bhi(v.x);
    x[i*8+2]+=blo(v.y); x[i*8+3]+=bhi(v.y);
    x[i*8+4]+=blo(v.z); x[i*8+5]+=bhi(v.z);
    x[i*8+6]+=blo(v.w); x[i*8+7]+=bhi(v.w);
  }
#pragma unroll
  for(int k=0;k<64;k++) x[k] = fmaxf(x[k], 0.f);
  float wsum = a3b[0];
  for(int d=0; d<64; d++){
    float v = fmaxf(dot64(&Wt[d*64], x) + bs[d], 0.f);
    wsum += v * a3s[d];
  }
  wlog[e] = wsum;
}

// one wave per user: softmax over its CSR segment + weighted x_ia accumulate + fused w_w GEMV
__global__ __launch_bounds__(256) void k_gather(const int* __restrict__ start, const int* __restrict__ c_s,
                                                const float* __restrict__ wlog,
                                                const bf16_t* __restrict__ xia,
                                                const float* __restrict__ ww, const float* __restrict__ wb,
                                                float* __restrict__ out){
  __shared__ float Ws[4096];      // ww row-major: Ws[k*64+d]
  __shared__ float bsh[64];
  __shared__ float hsh[4][64];
  stage_w(ww, Ws, threadIdx.x, 256);
  if(threadIdx.x < 64) bsh[threadIdx.x] = wb[threadIdx.x];
  __syncthreads();
  int w = threadIdx.x >> 6, lane = threadIdx.x & 63;
  int u = blockIdx.x*4 + w;                 // grid = U_N/4 exactly (25000)
  int s0 = start[u], s1 = start[u+1];
  int n = s1 - s0;
  int nq = (n + 63) >> 6;
  float tq[4]; int cq[4];
  float m = -1e30f;
  for(int q=0; q<nq; ++q){
    int j = q*64 + lane;
    float t = (j<n) ? wlog[s0+j] : -1e30f;
    int c   = (j<n) ? c_s[s0+j] : 0;
    if(q<4){ tq[q]=t; cq[q]=c; }
    m = fmaxf(m, t);
  }
#pragma unroll
  for(int off=32; off>=1; off>>=1) m = fmaxf(m, __shfl_xor(m, off));
  float ssum = 0.f;
  for(int q=0; q<nq; ++q){
    int j = q*64 + lane;
    float t = (q<4) ? tq[q] : ((j<n) ? wlog[s0+j] : -1e30f);
    float e = (j<n) ? __expf(t - m) : 0.f;
    if(q<4) tq[q] = e;
    ssum += e;
  }
#pragma unroll
  for(int off=32; off>=1; off>>=1) ssum += __shfl_xor(ssum, off);
  float inv = (n>0) ? (1.f/ssum) : 0.f;
  float acc = 0.f;
  for(int q=0; q<nq; ++q){
    float ev; int cv;
    if(q<4){ ev = tq[q]; cv = cq[q]; }
    else {
      int j = q*64 + lane;
      float t = (j<n) ? wlog[s0+j] : -1e30f;
      cv = (j<n) ? c_s[s0+j] : 0;
      ev = (j<n) ? __expf(t - m) : 0.f;
    }
    int lim = n - q*64; if(lim > 64) lim = 64;
    for(int l=0; l<lim; ++l){
      float v = __shfl(ev, l) * inv;
      int  c  = __shfl(cv, l);
      acc += __bfloat162float(xia[(size_t)c*64 + lane]) * v;
    }
  }
  hsh[w][lane] = acc;
  __syncthreads();
  const float* hp = hsh[w];
  float o = bsh[lane];
  for(int k=0; k<64; ++k) o += hp[k] * Ws[k*64 + lane];
  out[(size_t)u*64 + lane] = o;
}

extern "C" void kernel_launch(void* const* d_in, const int* in_sizes, int n_in,
                              void* d_out, int out_size, void* d_ws, size_t ws_size,
                              hipStream_t stream){
  (void)in_sizes; (void)n_in; (void)out_size; (void)ws_size;
  const float4* user_feat  = (const float4*)d_in[0];
  const float4* item_feat  = (const float4*)d_in[1];
  const float*  rating_feat= (const float*)d_in[2];
  const int*    rows       = (const int*)d_in[3];
  const int*    cols       = (const int*)d_in[4];
  const int*    rats       = (const int*)d_in[5];
  const float* gv_w1 = (const float*)d_in[6];
  const float* gv_b1 = (const float*)d_in[7];
  const float* gv_w2 = (const float*)d_in[8];
  const float* gv_b2 = (const float*)d_in[9];
  const float* att_w1= (const float*)d_in[10];
  const float* att_b1= (const float*)d_in[11];
  const float* att_w2= (const float*)d_in[12];
  const float* att_b2= (const float*)d_in[13];
  const float* att_w3= (const float*)d_in[14];
  const float* att_b3= (const float*)d_in[15];
  const float* w_w   = (const float*)d_in[16];
  const float* w_b   = (const float*)d_in[17];
  float* out = (float*)d_out;

  char* ws = (char*)d_ws; size_t off = 0;
  auto take = [&](size_t b)->char*{ char* p = ws + off; off = (off + b + 255) & ~(size_t)255; return p; };
  float*  item_part  = (float*) take((size_t)I_N*64*4);     // 12.8 MB
  bf16_t* user_part  = (bf16_t*)take((size_t)U_N*64*2);     // 12.8 MB
  float*  rating_part= (float*) take((size_t)R_N*64*4);
  bf16_t* xia_t      = (bf16_t*)take((size_t)C_N*64*2);     // 32 MB
  bf16_t* xa1_t      = (bf16_t*)take((size_t)C_N*64*2);     // 32 MB
  float*  wlog_s     = (float*) take((size_t)E_N*4);        // 8 MB
  int*    c_s        = (int*)   take((size_t)E_N*4);        // 8 MB
  int*    u_s        = (int*)   take((size_t)E_N*4);        // 8 MB
  int*    cnt        = (int*)   take((size_t)U_N*4);
  int*    fill       = (int*)   take((size_t)U_N*4);
  int*    start      = (int*)   take((size_t)(NBLK_U*256)*4);
  int*    bsum       = (int*)   take((size_t)512*4);

  // CSR build (independent of feature compute; only needs index arrays)
  k_zero  <<<(U_N+255)/256, 256, 0, stream>>>(cnt, fill);
  k_count <<<(E_N+255)/256, 256, 0, stream>>>(cols, cnt);
  k_scanA <<<NBLK_U, 256, 0, stream>>>(cnt, start, bsum);
  k_scanB <<<1, 512, 0, stream>>>(bsum, NBLK_U);
  k_scanC <<<NBLK_U, 256, 0, stream>>>(start, bsum);
  k_place <<<(E_N+255)/256, 256, 0, stream>>>(rows, cols, rats, start, fill, u_s, c_s);
  // dense precompute
  k_ratpart <<<1, 320, 0, stream>>>(rating_feat, gv_w1, gv_b1, rating_part);
  k_itempart<<<(I_N+255)/256, 256, 0, stream>>>(item_feat, gv_w1, item_part);
  k_userpart<<<(U_N+255)/256, 256, 0, stream>>>(user_feat, att_w1, att_b1, user_part);
  k_combo   <<<(C_N+255)/256, 256, 0, stream>>>(item_part, rating_part, gv_w2, gv_b2, att_w1, xia_t, xa1_t);
  // per-edge logits in CSR order
  k_edge    <<<(E_N+255)/256, 256, 0, stream>>>(u_s, c_s, (const uint4*)xa1_t, (const uint4*)user_part,
                                                att_w2, att_b2, att_w3, att_b3, wlog_s);
  // fused softmax + aggregate + output projection
  k_gather  <<<U_N/4, 256, 0, stream>>>(start, c_s, wlog_s, xia_t, w_w, w_b, out);
}

// Round 4
// 758.988 us; speedup vs baseline: 1.7224x; 1.3202x over previous
//
#include <hip/hip_runtime.h>
#include <hip/hip_bf16.h>

#define U_N 100000
#define I_N 50000
#define E_N 2000000
#define R_N 5
#define C_N (I_N*R_N)   // 250000 (item,rating) combos
#define NBLK_U 391      // ceil(100000/256)
#define NBLK_E 7813     // ceil(2000000/256)

typedef __hip_bfloat16 bf16_t;
typedef unsigned short u16;
typedef __attribute__((ext_vector_type(8))) short bf16x8;
typedef __attribute__((ext_vector_type(4))) float f32x4;

__device__ __forceinline__ float blo(unsigned u){ return __uint_as_float(u<<16); }
__device__ __forceinline__ float bhi(unsigned u){ return __uint_as_float(u & 0xffff0000u); }

__device__ __forceinline__ unsigned pkbf(float a, float b){
  __hip_bfloat162 t = __float22bfloat162_rn(float2{a,b});
  union { __hip_bfloat162 h; unsigned u; } cv; cv.h = t; return cv.u;
}

__device__ __forceinline__ void load64_f32(const float4* p, float* x){
#pragma unroll
  for(int q=0;q<16;q++){
    float4 v = p[q];
    x[q*4+0]=v.x; x[q*4+1]=v.y; x[q*4+2]=v.z; x[q*4+3]=v.w;
  }
}

__device__ __forceinline__ void load64_bf16(const uint4* p, float* x){
#pragma unroll
  for(int i=0;i<8;i++){
    uint4 v = p[i];
    x[i*8+0]=blo(v.x); x[i*8+1]=bhi(v.x);
    x[i*8+2]=blo(v.y); x[i*8+3]=bhi(v.y);
    x[i*8+4]=blo(v.z); x[i*8+5]=bhi(v.z);
    x[i*8+6]=blo(v.w); x[i*8+7]=bhi(v.w);
  }
}

// stage rows [koff..koff+63] of W[K][64] transposed into LDS: Wt[d*64+k]
__device__ __forceinline__ void stage_wt(const float* w, int koff, float* Wt, int tid, int nth){
  for(int idx=tid; idx<4096; idx+=nth){
    int d = idx & 63, k = idx >> 6;
    Wt[d*64+k] = w[(size_t)(koff+k)*64 + d];
  }
}
__device__ __forceinline__ void stage_w(const float* w, float* Ws, int tid, int nth){
  for(int idx=tid; idx<4096; idx+=nth) Ws[idx] = w[idx];
}

__device__ __forceinline__ float dot64(const float* Wrow, const float* x){
  const float4* wr = (const float4*)Wrow;
  float a0=0.f,a1=0.f,a2=0.f,a3=0.f;
#pragma unroll
  for(int q=0;q<16;q++){
    float4 w = wr[q];
    a0 += x[q*4+0]*w.x;
    a1 += x[q*4+1]*w.y;
    a2 += x[q*4+2]*w.z;
    a3 += x[q*4+3]*w.w;
  }
  return (a0+a1)+(a2+a3);
}

// ---------------- CSR build ----------------
__global__ __launch_bounds__(256) void k_zero(int* cnt, int* fill){
  int i = blockIdx.x*256 + threadIdx.x;
  if(i < U_N){ cnt[i]=0; fill[i]=0; }
}

__global__ __launch_bounds__(256) void k_count(const int* __restrict__ cols, int* __restrict__ cnt){
  int e = blockIdx.x*256 + threadIdx.x; if(e >= E_N) return;
  atomicAdd(cnt + cols[e], 1);
}

__global__ __launch_bounds__(256) void k_scanA(const int* __restrict__ cnt, int* __restrict__ start,
                                               int* __restrict__ bsum){
  __shared__ int s[256];
  int t = threadIdx.x, i = blockIdx.x*256 + t;
  int v = (i < U_N) ? cnt[i] : 0;
  s[t] = v; __syncthreads();
  for(int off=1; off<256; off<<=1){
    int x = (t>=off) ? s[t-off] : 0;
    __syncthreads();
    s[t] += x;
    __syncthreads();
  }
  start[i] = s[t] - v;
  if(t == 255) bsum[blockIdx.x] = s[255];
}

__global__ void k_scanB(int* bsum, int n){
  __shared__ int s[512];
  int t = threadIdx.x;
  int v = (t < n) ? bsum[t] : 0;
  s[t] = v; __syncthreads();
  for(int off=1; off<512; off<<=1){
    int x = (t>=off) ? s[t-off] : 0;
    __syncthreads();
    s[t] += x;
    __syncthreads();
  }
  if(t < n) bsum[t] = s[t] - v;
}

__global__ __launch_bounds__(256) void k_scanC(int* start, const int* __restrict__ bsum){
  int i = blockIdx.x*256 + threadIdx.x;
  start[i] += bsum[blockIdx.x];
}

__global__ __launch_bounds__(256) void k_place(const int* __restrict__ rows, const int* __restrict__ cols,
                                               const int* __restrict__ rats,
                                               const int* __restrict__ start, int* __restrict__ fill,
                                               int* __restrict__ u_s, int* __restrict__ c_s){
  int e = blockIdx.x*256 + threadIdx.x; if(e >= E_N) return;
  int u = cols[e];
  int pos = start[u] + atomicAdd(fill + u, 1);
  u_s[pos] = u;
  c_s[pos] = rows[e]*5 + rats[e];
}

// ---------------- dense precompute ----------------
__global__ void k_ratpart(const float* __restrict__ rf, const float* __restrict__ w1,
                          const float* __restrict__ b1, float* __restrict__ out){
  int t = threadIdx.x; if(t >= R_N*64) return;
  int r = t>>6, d = t&63;
  float acc = b1[d];
  for(int k=0;k<64;k++) acc += rf[r*64 + k] * w1[(64+k)*64 + d];
  out[t] = acc;
}

// w2t_g[d*64+k] = bf16(att_w2[k*64+d])  (transposed bf16 copy for MFMA B-frags)
__global__ __launch_bounds__(256) void k_prepw(const float* __restrict__ a2w, u16* __restrict__ w2t){
  int idx = blockIdx.x*256 + threadIdx.x; if(idx >= 4096) return;
  int d = idx >> 6, k = idx & 63;
  __hip_bfloat16 h = __float2bfloat16(a2w[k*64 + d]);
  union { __hip_bfloat16 x; u16 u; } cv; cv.x = h;
  w2t[idx] = cv.u;
}

__global__ __launch_bounds__(256) void k_itempart(const float4* __restrict__ itemf,
                                                  const float* __restrict__ w1,
                                                  float* __restrict__ out){
  __shared__ float Wt[4096];
  stage_wt(w1, 0, Wt, threadIdx.x, 256);
  __syncthreads();
  int i = blockIdx.x*256 + threadIdx.x; if(i >= I_N) return;
  float x[64]; load64_f32(itemf + (size_t)i*16, x);
  float* orow = out + (size_t)i*64;
  for(int d=0; d<64; d++) orow[d] = dot64(&Wt[d*64], x);
}

__global__ __launch_bounds__(256) void k_userpart(const float4* __restrict__ userf,
                                                  const float* __restrict__ a1w,
                                                  const float* __restrict__ a1b,
                                                  bf16_t* __restrict__ out){
  __shared__ float Wt[4096]; __shared__ float bs[64];
  stage_wt(a1w, 64, Wt, threadIdx.x, 256);
  if(threadIdx.x < 64) bs[threadIdx.x] = a1b[threadIdx.x];
  __syncthreads();
  int u = blockIdx.x*256 + threadIdx.x; if(u >= U_N) return;
  float x[64]; load64_f32(userf + (size_t)u*16, x);
  bf16_t* orow = out + (size_t)u*64;
  for(int d=0; d<64; d++) orow[d] = __float2bfloat16(dot64(&Wt[d*64], x) + bs[d]);
}

__global__ __launch_bounds__(256) void k_combo(const float* __restrict__ item_part,
                                               const float* __restrict__ rating_part,
                                               const float* __restrict__ w2, const float* __restrict__ b2,
                                               const float* __restrict__ a1w,
                                               bf16_t* __restrict__ xia_t, bf16_t* __restrict__ xa1_t){
  __shared__ float W2t[4096]; __shared__ float A1t[4096]; __shared__ float b2s[64];
  stage_wt(w2, 0, W2t, threadIdx.x, 256);
  stage_wt(a1w, 0, A1t, threadIdx.x, 256);
  if(threadIdx.x < 64) b2s[threadIdx.x] = b2[threadIdx.x];
  __syncthreads();
  int c = blockIdx.x*256 + threadIdx.x; if(c >= C_N) return;
  int i = c/5, r = c - i*5;
  float x[64], y[64];
  const float4* ip = (const float4*)(item_part + (size_t)i*64);
  const float4* rp = (const float4*)(rating_part + (size_t)r*64);
#pragma unroll
  for(int q=0;q<16;q++){
    float4 a = ip[q], b = rp[q];
    x[q*4+0] = fmaxf(a.x+b.x, 0.f);
    x[q*4+1] = fmaxf(a.y+b.y, 0.f);
    x[q*4+2] = fmaxf(a.z+b.z, 0.f);
    x[q*4+3] = fmaxf(a.w+b.w, 0.f);
  }
  bf16_t* orow = xia_t + (size_t)c*64;
  for(int d=0; d<64; d++){
    float v = fmaxf(dot64(&W2t[d*64], x) + b2s[d], 0.f);
    y[d] = v;
    orow[d] = __float2bfloat16(v);
  }
  bf16_t* orow2 = xa1_t + (size_t)c*64;
  for(int d=0; d<64; d++)
    orow2[d] = __float2bfloat16(dot64(&A1t[d*64], y));
}

// ---------------- MFMA edge-logit kernel ----------------
// Block: 256 edges, 4 waves. A-tile a1[256][64] bf16 in LDS (XOR-swizzled),
// B = att_w2 (bf16, pre-transposed w2t[d][k]). Per wave: 4 edge-tiles x 4 n-tiles
// x 2 k-steps of mfma_f32_16x16x32_bf16; epilogue relu*a3 + shfl_xor reduce.
__global__ __launch_bounds__(256) void k_edge_mfma(const int* __restrict__ u_s, const int* __restrict__ c_s,
                                                   const uint4* __restrict__ xa1p, const uint4* __restrict__ userp,
                                                   const uint4* __restrict__ w2t_g,
                                                   const float* __restrict__ a2b,
                                                   const float* __restrict__ a3w, const float* __restrict__ a3b,
                                                   float* __restrict__ wlog){
  __shared__ uint4 A_u4[2048];    // 256 edges x 128B
  __shared__ uint4 W_u4[512];     // 64 d-rows x 128B (w2t, swizzled)
  __shared__ float b2s[64];
  __shared__ float a3s[64];
  const int tid = threadIdx.x;

  // stage W2t (coalesced 8KB copy, swizzled store)
  for(int cid = tid; cid < 512; cid += 256){
    int d = cid >> 3, ch = cid & 7;
    W_u4[d*8 + (ch ^ (d&7))] = w2t_g[cid];
  }
  if(tid < 64){ b2s[tid] = a2b[tid]; a3s[tid] = a3w[tid]; }

  // stage A: a1 = relu(xa1[c] + user_part[u]); 8 lanes per edge, 8 iters
  const int base = blockIdx.x*256;
  const int ch = tid & 7;
#pragma unroll
  for(int it=0; it<8; ++it){
    int s = it*32 + (tid>>3);
    int e = base + s;
    uint4 xv = {0,0,0,0}, uv = {0,0,0,0};
    if(e < E_N){
      int c = c_s[e], u = u_s[e];
      xv = xa1p[(size_t)c*8 + ch];
      uv = userp[(size_t)u*8 + ch];
    }
    uint4 o;
    o.x = pkbf(fmaxf(blo(xv.x)+blo(uv.x),0.f), fmaxf(bhi(xv.x)+bhi(uv.x),0.f));
    o.y = pkbf(fmaxf(blo(xv.y)+blo(uv.y),0.f), fmaxf(bhi(xv.y)+bhi(uv.y),0.f));
    o.z = pkbf(fmaxf(blo(xv.z)+blo(uv.z),0.f), fmaxf(bhi(xv.z)+bhi(uv.z),0.f));
    o.w = pkbf(fmaxf(blo(xv.w)+blo(uv.w),0.f), fmaxf(bhi(xv.w)+bhi(uv.w),0.f));
    A_u4[s*8 + (ch ^ (s&7))] = o;
  }
  __syncthreads();

  const int l = tid & 63, w = tid >> 6;
  const int lr = l & 15;          // frag row/col-in-tile
  const int g  = l >> 4;          // k-group
  // B fragments: lane l holds W2[k=(g*8+j)+32*kk][d = nt*16+lr]
  bf16x8 bf[4][2];
#pragma unroll
  for(int nt=0; nt<4; ++nt){
#pragma unroll
    for(int kk=0; kk<2; ++kk){
      int d = nt*16 + lr;
      bf[nt][kk] = *(const bf16x8*)&W_u4[d*8 + ((kk*4 + g) ^ (d&7))];
    }
  }
  float b2v[4], a3v[4];
#pragma unroll
  for(int nt=0; nt<4; ++nt){ b2v[nt] = b2s[nt*16 + lr]; a3v[nt] = a3s[nt*16 + lr]; }
  const float a3b0 = a3b[0];

#pragma unroll
  for(int t=0; t<4; ++t){
    int s = w*64 + t*16 + lr;     // block-local edge row
    bf16x8 af0 = *(const bf16x8*)&A_u4[s*8 + ((0*4 + g) ^ (s&7))];
    bf16x8 af1 = *(const bf16x8*)&A_u4[s*8 + ((1*4 + g) ^ (s&7))];
    f32x4 acc[4];
#pragma unroll
    for(int nt=0; nt<4; ++nt){
      f32x4 c0 = { b2v[nt], b2v[nt], b2v[nt], b2v[nt] };
      c0 = __builtin_amdgcn_mfma_f32_16x16x32_bf16(af0, bf[nt][0], c0, 0, 0, 0);
      c0 = __builtin_amdgcn_mfma_f32_16x16x32_bf16(af1, bf[nt][1], c0, 0, 0, 0);
      acc[nt] = c0;
    }
    float s0=0.f, s1=0.f, s2=0.f, s3=0.f;
#pragma unroll
    for(int nt=0; nt<4; ++nt){
      s0 += fmaxf(acc[nt][0], 0.f) * a3v[nt];
      s1 += fmaxf(acc[nt][1], 0.f) * a3v[nt];
      s2 += fmaxf(acc[nt][2], 0.f) * a3v[nt];
      s3 += fmaxf(acc[nt][3], 0.f) * a3v[nt];
    }
#pragma unroll
    for(int mask=1; mask<16; mask<<=1){
      s0 += __shfl_xor(s0, mask);
      s1 += __shfl_xor(s1, mask);
      s2 += __shfl_xor(s2, mask);
      s3 += __shfl_xor(s3, mask);
    }
    if(lr == 0){
      int e0 = base + w*64 + t*16 + g*4;   // rows (l>>4)*4 + reg
      if(e0+0 < E_N) wlog[e0+0] = s0 + a3b0;
      if(e0+1 < E_N) wlog[e0+1] = s1 + a3b0;
      if(e0+2 < E_N) wlog[e0+2] = s2 + a3b0;
      if(e0+3 < E_N) wlog[e0+3] = s3 + a3b0;
    }
  }
}

// one wave per user: softmax over CSR segment + weighted x_ia accumulate + fused w_w GEMV
__global__ __launch_bounds__(256) void k_gather(const int* __restrict__ start, const int* __restrict__ c_s,
                                                const float* __restrict__ wlog,
                                                const bf16_t* __restrict__ xia,
                                                const float* __restrict__ ww, const float* __restrict__ wb,
                                                float* __restrict__ out){
  __shared__ float Ws[4096];
  __shared__ float bsh[64];
  __shared__ float hsh[4][64];
  stage_w(ww, Ws, threadIdx.x, 256);
  if(threadIdx.x < 64) bsh[threadIdx.x] = wb[threadIdx.x];
  __syncthreads();
  int w = threadIdx.x >> 6, lane = threadIdx.x & 63;
  int u = blockIdx.x*4 + w;
  int s0 = start[u], s1 = start[u+1];
  int n = s1 - s0;
  int nq = (n + 63) >> 6;
  float tq[4]; int cq[4];
  float m = -1e30f;
  for(int q=0; q<nq; ++q){
    int j = q*64 + lane;
    float t = (j<n) ? wlog[s0+j] : -1e30f;
    int c   = (j<n) ? c_s[s0+j] : 0;
    if(q<4){ tq[q]=t; cq[q]=c; }
    m = fmaxf(m, t);
  }
#pragma unroll
  for(int off=32; off>=1; off>>=1) m = fmaxf(m, __shfl_xor(m, off));
  float ssum = 0.f;
  for(int q=0; q<nq; ++q){
    int j = q*64 + lane;
    float t = (q<4) ? tq[q] : ((j<n) ? wlog[s0+j] : -1e30f);
    float e = (j<n) ? __expf(t - m) : 0.f;
    if(q<4) tq[q] = e;
    ssum += e;
  }
#pragma unroll
  for(int off=32; off>=1; off>>=1) ssum += __shfl_xor(ssum, off);
  float inv = (n>0) ? (1.f/ssum) : 0.f;
  float acc = 0.f;
  for(int q=0; q<nq; ++q){
    float ev; int cv;
    if(q<4){ ev = tq[q]; cv = cq[q]; }
    else {
      int j = q*64 + lane;
      float t = (j<n) ? wlog[s0+j] : -1e30f;
      cv = (j<n) ? c_s[s0+j] : 0;
      ev = (j<n) ? __expf(t - m) : 0.f;
    }
    int lim = n - q*64; if(lim > 64) lim = 64;
    for(int ll=0; ll<lim; ++ll){
      float v = __shfl(ev, ll) * inv;
      int  c  = __shfl(cv, ll);
      acc += __bfloat162float(xia[(size_t)c*64 + lane]) * v;
    }
  }
  hsh[w][lane] = acc;
  __syncthreads();
  const float* hp = hsh[w];
  float o = bsh[lane];
  for(int k=0; k<64; ++k) o += hp[k] * Ws[k*64 + lane];
  out[(size_t)u*64 + lane] = o;
}

extern "C" void kernel_launch(void* const* d_in, const int* in_sizes, int n_in,
                              void* d_out, int out_size, void* d_ws, size_t ws_size,
                              hipStream_t stream){
  (void)in_sizes; (void)n_in; (void)out_size; (void)ws_size;
  const float4* user_feat  = (const float4*)d_in[0];
  const float4* item_feat  = (const float4*)d_in[1];
  const float*  rating_feat= (const float*)d_in[2];
  const int*    rows       = (const int*)d_in[3];
  const int*    cols       = (const int*)d_in[4];
  const int*    rats       = (const int*)d_in[5];
  const float* gv_w1 = (const float*)d_in[6];
  const float* gv_b1 = (const float*)d_in[7];
  const float* gv_w2 = (const float*)d_in[8];
  const float* gv_b2 = (const float*)d_in[9];
  const float* att_w1= (const float*)d_in[10];
  const float* att_b1= (const float*)d_in[11];
  const float* att_w2= (const float*)d_in[12];
  const float* att_b2= (const float*)d_in[13];
  const float* att_w3= (const float*)d_in[14];
  const float* att_b3= (const float*)d_in[15];
  const float* w_w   = (const float*)d_in[16];
  const float* w_b   = (const float*)d_in[17];
  float* out = (float*)d_out;

  char* ws = (char*)d_ws; size_t off = 0;
  auto take = [&](size_t b)->char*{ char* p = ws + off; off = (off + b + 255) & ~(size_t)255; return p; };
  float*  item_part  = (float*) take((size_t)I_N*64*4);
  bf16_t* user_part  = (bf16_t*)take((size_t)U_N*64*2);
  float*  rating_part= (float*) take((size_t)R_N*64*4);
  bf16_t* xia_t      = (bf16_t*)take((size_t)C_N*64*2);
  bf16_t* xa1_t      = (bf16_t*)take((size_t)C_N*64*2);
  float*  wlog_s     = (float*) take((size_t)E_N*4);
  int*    c_s        = (int*)   take((size_t)E_N*4);
  int*    u_s        = (int*)   take((size_t)E_N*4);
  int*    cnt        = (int*)   take((size_t)U_N*4);
  int*    fill       = (int*)   take((size_t)U_N*4);
  int*    start      = (int*)   take((size_t)(NBLK_U*256)*4);
  int*    bsum       = (int*)   take((size_t)512*4);
  u16*    w2t_g      = (u16*)   take((size_t)4096*2);

  // CSR build
  k_zero  <<<(U_N+255)/256, 256, 0, stream>>>(cnt, fill);
  k_count <<<(E_N+255)/256, 256, 0, stream>>>(cols, cnt);
  k_scanA <<<NBLK_U, 256, 0, stream>>>(cnt, start, bsum);
  k_scanB <<<1, 512, 0, stream>>>(bsum, NBLK_U);
  k_scanC <<<NBLK_U, 256, 0, stream>>>(start, bsum);
  k_place <<<(E_N+255)/256, 256, 0, stream>>>(rows, cols, rats, start, fill, u_s, c_s);
  // dense precompute
  k_ratpart <<<1, 320, 0, stream>>>(rating_feat, gv_w1, gv_b1, rating_part);
  k_prepw   <<<16, 256, 0, stream>>>(att_w2, w2t_g);
  k_itempart<<<(I_N+255)/256, 256, 0, stream>>>(item_feat, gv_w1, item_part);
  k_userpart<<<(U_N+255)/256, 256, 0, stream>>>(user_feat, att_w1, att_b1, user_part);
  k_combo   <<<(C_N+255)/256, 256, 0, stream>>>(item_part, rating_part, gv_w2, gv_b2, att_w1, xia_t, xa1_t);
  // per-edge logits (MFMA)
  k_edge_mfma<<<NBLK_E, 256, 0, stream>>>(u_s, c_s, (const uint4*)xa1_t, (const uint4*)user_part,
                                          (const uint4*)w2t_g, att_b2, att_w3, att_b3, wlog_s);
  // fused softmax + aggregate + output projection
  k_gather  <<<U_N/4, 256, 0, stream>>>(start, c_s, wlog_s, xia_t, w_w, w_b, out);
}

// Round 5
// 507.469 us; speedup vs baseline: 2.5760x; 1.4956x over previous
//
#include <hip/hip_runtime.h>
#include <hip/hip_bf16.h>

#define U_N 100000
#define I_N 50000
#define E_N 2000000
#define R_N 5
#define C_N (I_N*R_N)   // 250000 combos
#define NBLK_U 391      // ceil(100000/256)
#define NBLK_E 7813     // ceil(2000000/256)
#define NBLK_C 1954     // ceil(250000/128)

typedef __hip_bfloat16 bf16_t;
typedef unsigned short u16;
typedef __attribute__((ext_vector_type(8))) short bf16x8;
typedef __attribute__((ext_vector_type(4))) float f32x4;

__device__ __forceinline__ float blo(unsigned u){ return __uint_as_float(u<<16); }
__device__ __forceinline__ float bhi(unsigned u){ return __uint_as_float(u & 0xffff0000u); }
__device__ __forceinline__ unsigned pkbf(float a, float b){
  __hip_bfloat162 t = __float22bfloat162_rn(float2{a,b});
  union { __hip_bfloat162 h; unsigned u; } cv; cv.h = t; return cv.u;
}
__device__ __forceinline__ u16 f2b(float v){
  union { __hip_bfloat16 h; u16 u; } cv; cv.h = __float2bfloat16(v); return cv.u;
}

// ---------------- CSR build ----------------
__global__ __launch_bounds__(256) void k_zero(int* cnt, int* fill){
  int i = blockIdx.x*256 + threadIdx.x;
  if(i < U_N){ cnt[i]=0; fill[i]=0; }
}

__global__ __launch_bounds__(256) void k_count(const int* __restrict__ cols, int* __restrict__ cnt){
  int e = blockIdx.x*256 + threadIdx.x; if(e >= E_N) return;
  atomicAdd(cnt + cols[e], 1);
}

__global__ __launch_bounds__(256) void k_scanA(const int* __restrict__ cnt, int* __restrict__ start,
                                               int* __restrict__ bsum){
  __shared__ int s[256];
  int t = threadIdx.x, i = blockIdx.x*256 + t;
  int v = (i < U_N) ? cnt[i] : 0;
  s[t] = v; __syncthreads();
  for(int off=1; off<256; off<<=1){
    int x = (t>=off) ? s[t-off] : 0;
    __syncthreads();
    s[t] += x;
    __syncthreads();
  }
  start[i] = s[t] - v;
  if(t == 255) bsum[blockIdx.x] = s[255];
}

__global__ void k_scanB(int* bsum, int n){
  __shared__ int s[512];
  int t = threadIdx.x;
  int v = (t < n) ? bsum[t] : 0;
  s[t] = v; __syncthreads();
  for(int off=1; off<512; off<<=1){
    int x = (t>=off) ? s[t-off] : 0;
    __syncthreads();
    s[t] += x;
    __syncthreads();
  }
  if(t < n) bsum[t] = s[t] - v;
}

__global__ __launch_bounds__(256) void k_scanC(int* start, const int* __restrict__ bsum){
  int i = blockIdx.x*256 + threadIdx.x;
  start[i] += bsum[blockIdx.x];
}

__global__ __launch_bounds__(256) void k_place(const int* __restrict__ rows, const int* __restrict__ cols,
                                               const int* __restrict__ rats,
                                               const int* __restrict__ start, int* __restrict__ fill,
                                               int* __restrict__ u_s, int* __restrict__ c_s){
  int e = blockIdx.x*256 + threadIdx.x; if(e >= E_N) return;
  int u = cols[e];
  int pos = start[u] + atomicAdd(fill + u, 1);
  u_s[pos] = u;
  c_s[pos] = rows[e]*5 + rats[e];
}

// ---------------- tiny precompute ----------------
// rating_part[r][d] = gv_b1[d] + sum_k rf[r][k] * gv_w1[64+k][d]
__global__ void k_ratpart(const float* __restrict__ rf, const float* __restrict__ w1,
                          const float* __restrict__ b1, float* __restrict__ out){
  int t = threadIdx.x; if(t >= R_N*64) return;
  int r = t>>6, d = t&63;
  float acc = b1[d];
  for(int k=0;k<64;k++) acc += rf[r*64 + k] * w1[(64+k)*64 + d];
  out[t] = acc;
}

// 5 transposed bf16 weight tables: dst[d*64+k] = bf16(src[(ko+k)*64+d])
__global__ __launch_bounds__(256) void k_prepw5(const float* __restrict__ w1, const float* __restrict__ a1,
                                                const float* __restrict__ w2, const float* __restrict__ a2,
                                                u16* w1t, u16* u1t, u16* w2t, u16* a1t, u16* a2t){
  int idx = (blockIdx.x & 15)*256 + threadIdx.x;   // 0..4095
  int sec = blockIdx.x >> 4;
  int d = idx >> 6, k = idx & 63;
  const float* src; u16* dst; int ko = 0;
  switch(sec){
    case 0: src=w1; dst=w1t; break;
    case 1: src=a1; dst=u1t; ko=64; break;
    case 2: src=w2; dst=w2t; break;
    case 3: src=a1; dst=a1t; break;
    default: src=a2; dst=a2t; break;
  }
  dst[idx] = f2b(src[(size_t)(ko+k)*64 + d]);
}

// ---------------- MFMA row-GEMM: out[n][64](bf16) = in[n][64](f32) @ W (+bias) ----------------
template<bool BIAS>
__global__ __launch_bounds__(256) void k_rowgemm(const float4* __restrict__ in,
                                                 const uint4* __restrict__ wt,   // [64][8] bf16 chunks, [d][k]
                                                 const float* __restrict__ bias,
                                                 uint4* __restrict__ outp, int n){
  __shared__ uint4 A_u4[2048];    // 256 rows x 128B (swizzled), reused for output
  __shared__ uint4 W_u4[512];
  __shared__ float bsh[64];
  u16* A16 = (u16*)A_u4;
  const int tid = threadIdx.x;
  for(int cid = tid; cid < 512; cid += 256){
    int dd = cid >> 3, ch = cid & 7;
    W_u4[dd*8 + (ch ^ (dd&7))] = wt[cid];
  }
  if(BIAS && tid < 64) bsh[tid] = bias[tid];
  const int base = blockIdx.x*256;
  const int ch = tid & 7;
#pragma unroll
  for(int it=0; it<8; ++it){
    int s = it*32 + (tid>>3);
    int r = base + s;
    uint4 o = {0,0,0,0};
    if(r < n){
      const float4* p = in + (size_t)r*16 + ch*2;
      float4 v0 = p[0], v1 = p[1];
      o.x = pkbf(v0.x, v0.y); o.y = pkbf(v0.z, v0.w);
      o.z = pkbf(v1.x, v1.y); o.w = pkbf(v1.z, v1.w);
    }
    A_u4[s*8 + (ch ^ (s&7))] = o;
  }
  __syncthreads();
  const int l = tid & 63, w = tid >> 6;
  const int lr = l & 15, g = l >> 4;
  bf16x8 bfr[4][2];
#pragma unroll
  for(int nt=0; nt<4; ++nt)
#pragma unroll
    for(int kk=0; kk<2; ++kk){
      int d = nt*16 + lr;
      bfr[nt][kk] = *(const bf16x8*)&W_u4[d*8 + ((kk*4+g) ^ (d&7))];
    }
  float bv[4];
#pragma unroll
  for(int nt=0; nt<4; ++nt) bv[nt] = BIAS ? bsh[nt*16 + lr] : 0.f;
  // wave-private 64 rows: t-tiles
#pragma unroll
  for(int t=0; t<4; ++t){
    int s = w*64 + t*16 + lr;
    bf16x8 af0 = *(const bf16x8*)&A_u4[s*8 + ((0*4+g) ^ (s&7))];
    bf16x8 af1 = *(const bf16x8*)&A_u4[s*8 + ((1*4+g) ^ (s&7))];
    f32x4 acc[4];
#pragma unroll
    for(int nt=0; nt<4; ++nt){
      f32x4 c0 = { bv[nt], bv[nt], bv[nt], bv[nt] };
      c0 = __builtin_amdgcn_mfma_f32_16x16x32_bf16(af0, bfr[nt][0], c0, 0, 0, 0);
      c0 = __builtin_amdgcn_mfma_f32_16x16x32_bf16(af1, bfr[nt][1], c0, 0, 0, 0);
      acc[nt] = c0;
    }
    // write back into own rows of A tile (consumed above)
#pragma unroll
    for(int nt=0; nt<4; ++nt){
      int d = nt*16 + lr;
#pragma unroll
      for(int reg=0; reg<4; ++reg){
        int srow = w*64 + t*16 + g*4 + reg;
        A16[srow*64 + ((d>>3)^(srow&7))*8 + (d&7)] = f2b(acc[nt][reg]);
      }
    }
  }
  // wave-private cooperative store (no barrier needed)
#pragma unroll
  for(int it=0; it<8; ++it){
    int s = w*64 + it*8 + (l>>3);
    int c2 = l & 7;
    int r = base + s;
    if(r < n) outp[(size_t)r*8 + c2] = A_u4[s*8 + (c2 ^ (s&7))];
  }
}

// ---------------- combo: h1=relu(itemp+ratp); x_ia=relu(h1@W2+b2); xa1=x_ia@A1top ----------------
__global__ __launch_bounds__(256) void k_combo_mfma(const uint4* __restrict__ itemp,   // bf16 [I_N][64]
                                                    const float4* __restrict__ ratp,   // f32  [5][64]
                                                    const uint4* __restrict__ w2t_g, const uint4* __restrict__ a1t_g,
                                                    const float* __restrict__ b2,
                                                    uint4* __restrict__ xia_o, uint4* __restrict__ xa1_o){
  __shared__ uint4 A_u4[1024];    // 128 rows x 128B: h1, then xa1
  __shared__ uint4 X_u4[1024];    // x_ia tile
  __shared__ uint4 W2_u4[512];
  __shared__ uint4 A1_u4[512];
  __shared__ float4 rsh4[80];     // rating_part
  __shared__ float b2sh[64];
  u16* A16 = (u16*)A_u4;
  u16* X16 = (u16*)X_u4;
  const int tid = threadIdx.x;
  for(int cid = tid; cid < 512; cid += 256){
    int dd = cid >> 3, ch = cid & 7;
    W2_u4[dd*8 + (ch ^ (dd&7))] = w2t_g[cid];
    A1_u4[dd*8 + (ch ^ (dd&7))] = a1t_g[cid];
  }
  if(tid < 80) rsh4[tid] = ratp[tid];
  if(tid < 64) b2sh[tid] = b2[tid];
  __syncthreads();

  const int base = blockIdx.x*128;
  const int ch = tid & 7;
#pragma unroll
  for(int it=0; it<4; ++it){
    int s = it*32 + (tid>>3);
    int cidx = base + s;
    uint4 o = {0,0,0,0};
    if(cidx < C_N){
      int i = cidx/5, r = cidx - i*5;
      uint4 iv = itemp[(size_t)i*8 + ch];
      float4 r0 = rsh4[r*16 + ch*2], r1 = rsh4[r*16 + ch*2 + 1];
      o.x = pkbf(fmaxf(blo(iv.x)+r0.x,0.f), fmaxf(bhi(iv.x)+r0.y,0.f));
      o.y = pkbf(fmaxf(blo(iv.y)+r0.z,0.f), fmaxf(bhi(iv.y)+r0.w,0.f));
      o.z = pkbf(fmaxf(blo(iv.z)+r1.x,0.f), fmaxf(bhi(iv.z)+r1.y,0.f));
      o.w = pkbf(fmaxf(blo(iv.w)+r1.z,0.f), fmaxf(bhi(iv.w)+r1.w,0.f));
    }
    A_u4[s*8 + (ch ^ (s&7))] = o;
  }
  __syncthreads();

  const int l = tid & 63, w = tid >> 6;
  const int lr = l & 15, g = l >> 4;
  bf16x8 w2f[4][2], a1f[4][2];
#pragma unroll
  for(int nt=0; nt<4; ++nt)
#pragma unroll
    for(int kk=0; kk<2; ++kk){
      int d = nt*16 + lr;
      w2f[nt][kk] = *(const bf16x8*)&W2_u4[d*8 + ((kk*4+g) ^ (d&7))];
      a1f[nt][kk] = *(const bf16x8*)&A1_u4[d*8 + ((kk*4+g) ^ (d&7))];
    }
  float b2v[4];
#pragma unroll
  for(int nt=0; nt<4; ++nt) b2v[nt] = b2sh[nt*16 + lr];

#pragma unroll
  for(int t=0; t<2; ++t){
    int s = w*32 + t*16 + lr;
    // GEMM1: x_ia tile
    bf16x8 af0 = *(const bf16x8*)&A_u4[s*8 + ((0*4+g) ^ (s&7))];
    bf16x8 af1 = *(const bf16x8*)&A_u4[s*8 + ((1*4+g) ^ (s&7))];
#pragma unroll
    for(int nt=0; nt<4; ++nt){
      f32x4 c0 = { b2v[nt], b2v[nt], b2v[nt], b2v[nt] };
      c0 = __builtin_amdgcn_mfma_f32_16x16x32_bf16(af0, w2f[nt][0], c0, 0, 0, 0);
      c0 = __builtin_amdgcn_mfma_f32_16x16x32_bf16(af1, w2f[nt][1], c0, 0, 0, 0);
      int d = nt*16 + lr;
#pragma unroll
      for(int reg=0; reg<4; ++reg){
        int srow = w*32 + t*16 + g*4 + reg;
        X16[srow*64 + ((d>>3)^(srow&7))*8 + (d&7)] = f2b(fmaxf(c0[reg], 0.f));
      }
    }
    // GEMM2: xa1 tile (reads x_ia rows just written by this wave)
    bf16x8 xf0 = *(const bf16x8*)&X_u4[s*8 + ((0*4+g) ^ (s&7))];
    bf16x8 xf1 = *(const bf16x8*)&X_u4[s*8 + ((1*4+g) ^ (s&7))];
#pragma unroll
    for(int nt=0; nt<4; ++nt){
      f32x4 c0 = { 0.f, 0.f, 0.f, 0.f };
      c0 = __builtin_amdgcn_mfma_f32_16x16x32_bf16(xf0, a1f[nt][0], c0, 0, 0, 0);
      c0 = __builtin_amdgcn_mfma_f32_16x16x32_bf16(xf1, a1f[nt][1], c0, 0, 0, 0);
      int d = nt*16 + lr;
#pragma unroll
      for(int reg=0; reg<4; ++reg){
        int srow = w*32 + t*16 + g*4 + reg;
        A16[srow*64 + ((d>>3)^(srow&7))*8 + (d&7)] = f2b(c0[reg]);   // overwrite dead h1 rows
      }
    }
  }
  // wave-private cooperative stores
#pragma unroll
  for(int it=0; it<4; ++it){
    int s = w*32 + it*8 + (l>>3);
    int c2 = l & 7;
    int r = base + s;
    if(r < C_N){
      xia_o[(size_t)r*8 + c2] = X_u4[s*8 + (c2 ^ (s&7))];
      xa1_o[(size_t)r*8 + c2] = A_u4[s*8 + (c2 ^ (s&7))];
    }
  }
}

// ---------------- MFMA edge-logit kernel (unchanged from R4) ----------------
__global__ __launch_bounds__(256) void k_edge_mfma(const int* __restrict__ u_s, const int* __restrict__ c_s,
                                                   const uint4* __restrict__ xa1p, const uint4* __restrict__ userp,
                                                   const uint4* __restrict__ a2t_g,
                                                   const float* __restrict__ a2b,
                                                   const float* __restrict__ a3w, const float* __restrict__ a3b,
                                                   float* __restrict__ wlog){
  __shared__ uint4 A_u4[2048];
  __shared__ uint4 W_u4[512];
  __shared__ float b2s[64];
  __shared__ float a3s[64];
  const int tid = threadIdx.x;
  for(int cid = tid; cid < 512; cid += 256){
    int d = cid >> 3, ch = cid & 7;
    W_u4[d*8 + (ch ^ (d&7))] = a2t_g[cid];
  }
  if(tid < 64){ b2s[tid] = a2b[tid]; a3s[tid] = a3w[tid]; }
  const int base = blockIdx.x*256;
  const int ch = tid & 7;
#pragma unroll
  for(int it=0; it<8; ++it){
    int s = it*32 + (tid>>3);
    int e = base + s;
    uint4 xv = {0,0,0,0}, uv = {0,0,0,0};
    if(e < E_N){
      int c = c_s[e], u = u_s[e];
      xv = xa1p[(size_t)c*8 + ch];
      uv = userp[(size_t)u*8 + ch];
    }
    uint4 o;
    o.x = pkbf(fmaxf(blo(xv.x)+blo(uv.x),0.f), fmaxf(bhi(xv.x)+bhi(uv.x),0.f));
    o.y = pkbf(fmaxf(blo(xv.y)+blo(uv.y),0.f), fmaxf(bhi(xv.y)+bhi(uv.y),0.f));
    o.z = pkbf(fmaxf(blo(xv.z)+blo(uv.z),0.f), fmaxf(bhi(xv.z)+bhi(uv.z),0.f));
    o.w = pkbf(fmaxf(blo(xv.w)+blo(uv.w),0.f), fmaxf(bhi(xv.w)+bhi(uv.w),0.f));
    A_u4[s*8 + (ch ^ (s&7))] = o;
  }
  __syncthreads();
  const int l = tid & 63, w = tid >> 6;
  const int lr = l & 15;
  const int g  = l >> 4;
  bf16x8 bf[4][2];
#pragma unroll
  for(int nt=0; nt<4; ++nt)
#pragma unroll
    for(int kk=0; kk<2; ++kk){
      int d = nt*16 + lr;
      bf[nt][kk] = *(const bf16x8*)&W_u4[d*8 + ((kk*4 + g) ^ (d&7))];
    }
  float b2v[4], a3v[4];
#pragma unroll
  for(int nt=0; nt<4; ++nt){ b2v[nt] = b2s[nt*16 + lr]; a3v[nt] = a3s[nt*16 + lr]; }
  const float a3b0 = a3b[0];
#pragma unroll
  for(int t=0; t<4; ++t){
    int s = w*64 + t*16 + lr;
    bf16x8 af0 = *(const bf16x8*)&A_u4[s*8 + ((0*4 + g) ^ (s&7))];
    bf16x8 af1 = *(const bf16x8*)&A_u4[s*8 + ((1*4 + g) ^ (s&7))];
    f32x4 acc[4];
#pragma unroll
    for(int nt=0; nt<4; ++nt){
      f32x4 c0 = { b2v[nt], b2v[nt], b2v[nt], b2v[nt] };
      c0 = __builtin_amdgcn_mfma_f32_16x16x32_bf16(af0, bf[nt][0], c0, 0, 0, 0);
      c0 = __builtin_amdgcn_mfma_f32_16x16x32_bf16(af1, bf[nt][1], c0, 0, 0, 0);
      acc[nt] = c0;
    }
    float s0=0.f, s1=0.f, s2=0.f, s3=0.f;
#pragma unroll
    for(int nt=0; nt<4; ++nt){
      s0 += fmaxf(acc[nt][0], 0.f) * a3v[nt];
      s1 += fmaxf(acc[nt][1], 0.f) * a3v[nt];
      s2 += fmaxf(acc[nt][2], 0.f) * a3v[nt];
      s3 += fmaxf(acc[nt][3], 0.f) * a3v[nt];
    }
#pragma unroll
    for(int mask=1; mask<16; mask<<=1){
      s0 += __shfl_xor(s0, mask);
      s1 += __shfl_xor(s1, mask);
      s2 += __shfl_xor(s2, mask);
      s3 += __shfl_xor(s3, mask);
    }
    if(lr == 0){
      int e0 = base + w*64 + t*16 + g*4;
      if(e0+0 < E_N) wlog[e0+0] = s0 + a3b0;
      if(e0+1 < E_N) wlog[e0+1] = s1 + a3b0;
      if(e0+2 < E_N) wlog[e0+2] = s2 + a3b0;
      if(e0+3 < E_N) wlog[e0+3] = s3 + a3b0;
    }
  }
}

// ---------------- fused softmax + aggregate + output projection ----------------
__global__ __launch_bounds__(256) void k_gather(const int* __restrict__ start, const int* __restrict__ c_s,
                                                const float* __restrict__ wlog,
                                                const bf16_t* __restrict__ xia,
                                                const float* __restrict__ ww, const float* __restrict__ wb,
                                                float* __restrict__ out){
  __shared__ float Ws[4096];
  __shared__ float bsh[64];
  __shared__ float hsh[4][64];
  for(int idx=threadIdx.x; idx<4096; idx+=256) Ws[idx] = ww[idx];
  if(threadIdx.x < 64) bsh[threadIdx.x] = wb[threadIdx.x];
  __syncthreads();
  int w = threadIdx.x >> 6, lane = threadIdx.x & 63;
  int u = blockIdx.x*4 + w;
  int s0 = start[u], n = start[u+1] - s0;
  int nq = (n + 63) >> 6;
  float tq[4]; int cq[4];
  float m = -1e30f;
  for(int q=0; q<nq; ++q){
    int j = q*64 + lane;
    float t = (j<n) ? wlog[s0+j] : -1e30f;
    int c   = (j<n) ? c_s[s0+j] : 0;
    if(q<4){ tq[q]=t; cq[q]=c; }
    m = fmaxf(m, t);
  }
#pragma unroll
  for(int off=32; off>=1; off>>=1) m = fmaxf(m, __shfl_xor(m, off));
  float ssum = 0.f;
  for(int q=0; q<nq; ++q){
    int j = q*64 + lane;
    float t = (q<4) ? tq[q] : ((j<n) ? wlog[s0+j] : -1e30f);
    float e = (j<n) ? __expf(t - m) : 0.f;
    if(q<4) tq[q] = e;
    ssum += e;
  }
#pragma unroll
  for(int off=32; off>=1; off>>=1) ssum += __shfl_xor(ssum, off);
  float inv = (n>0) ? (1.f/ssum) : 0.f;
#pragma unroll
  for(int q=0; q<4; ++q) tq[q] *= inv;
  float acc = 0.f;
  for(int q=0; q<nq; ++q){
    float ev; int cv_;
    if(q<4){ ev = tq[q]; cv_ = cq[q]; }
    else {
      int j = q*64 + lane;
      float t = (j<n) ? wlog[s0+j] : -1e30f;
      cv_ = (j<n) ? c_s[s0+j] : 0;
      ev = (j<n) ? __expf(t - m)*inv : 0.f;
    }
    int lim = n - q*64; if(lim > 64) lim = 64;
    int ll = 0;
    for(; ll+4 <= lim; ll += 4){
      int   c0=__shfl(cv_,ll),  c1=__shfl(cv_,ll+1), c2=__shfl(cv_,ll+2), c3=__shfl(cv_,ll+3);
      float v0=__shfl(ev,ll),   v1=__shfl(ev,ll+1),  v2=__shfl(ev,ll+2),  v3=__shfl(ev,ll+3);
      float x0 = __bfloat162float(xia[(size_t)c0*64 + lane]);
      float x1 = __bfloat162float(xia[(size_t)c1*64 + lane]);
      float x2 = __bfloat162float(xia[(size_t)c2*64 + lane]);
      float x3 = __bfloat162float(xia[(size_t)c3*64 + lane]);
      acc = fmaf(x0, v0, acc); acc = fmaf(x1, v1, acc);
      acc = fmaf(x2, v2, acc); acc = fmaf(x3, v3, acc);
    }
    for(; ll<lim; ++ll){
      float v = __shfl(ev, ll); int c = __shfl(cv_, ll);
      acc = fmaf(__bfloat162float(xia[(size_t)c*64 + lane]), v, acc);
    }
  }
  hsh[w][lane] = acc;              // wave-private: no barrier needed
  const float* hp = hsh[w];
  float o = bsh[lane];
  for(int k=0; k<64; ++k) o = fmaf(hp[k], Ws[k*64 + lane], o);
  out[(size_t)u*64 + lane] = o;
}

extern "C" void kernel_launch(void* const* d_in, const int* in_sizes, int n_in,
                              void* d_out, int out_size, void* d_ws, size_t ws_size,
                              hipStream_t stream){
  (void)in_sizes; (void)n_in; (void)out_size; (void)ws_size;
  const float4* user_feat  = (const float4*)d_in[0];
  const float4* item_feat  = (const float4*)d_in[1];
  const float*  rating_feat= (const float*)d_in[2];
  const int*    rows       = (const int*)d_in[3];
  const int*    cols       = (const int*)d_in[4];
  const int*    rats       = (const int*)d_in[5];
  const float* gv_w1 = (const float*)d_in[6];
  const float* gv_b1 = (const float*)d_in[7];
  const float* gv_w2 = (const float*)d_in[8];
  const float* gv_b2 = (const float*)d_in[9];
  const float* att_w1= (const float*)d_in[10];
  const float* att_b1= (const float*)d_in[11];
  const float* att_w2= (const float*)d_in[12];
  const float* att_b2= (const float*)d_in[13];
  const float* att_w3= (const float*)d_in[14];
  const float* att_b3= (const float*)d_in[15];
  const float* w_w   = (const float*)d_in[16];
  const float* w_b   = (const float*)d_in[17];
  float* out = (float*)d_out;

  char* ws = (char*)d_ws; size_t off = 0;
  auto take = [&](size_t b)->char*{ char* p = ws + off; off = (off + b + 255) & ~(size_t)255; return p; };
  bf16_t* item_part  = (bf16_t*)take((size_t)I_N*64*2);     // 6.4 MB
  bf16_t* user_part  = (bf16_t*)take((size_t)U_N*64*2);     // 12.8 MB
  float*  rating_part= (float*) take((size_t)R_N*64*4);
  bf16_t* xia_t      = (bf16_t*)take((size_t)C_N*64*2);     // 32 MB
  bf16_t* xa1_t      = (bf16_t*)take((size_t)C_N*64*2);     // 32 MB
  float*  wlog_s     = (float*) take((size_t)E_N*4);        // 8 MB
  int*    c_s        = (int*)   take((size_t)E_N*4);        // 8 MB
  int*    u_s        = (int*)   take((size_t)E_N*4);        // 8 MB
  int*    cnt        = (int*)   take((size_t)U_N*4);
  int*    fill       = (int*)   take((size_t)U_N*4);
  int*    start      = (int*)   take((size_t)(NBLK_U*256)*4);
  int*    bsum       = (int*)   take((size_t)512*4);
  u16*    w1t        = (u16*)   take((size_t)4096*2);
  u16*    u1t        = (u16*)   take((size_t)4096*2);
  u16*    w2t        = (u16*)   take((size_t)4096*2);
  u16*    a1t        = (u16*)   take((size_t)4096*2);
  u16*    a2t        = (u16*)   take((size_t)4096*2);

  // CSR build
  k_zero  <<<(U_N+255)/256, 256, 0, stream>>>(cnt, fill);
  k_count <<<(E_N+255)/256, 256, 0, stream>>>(cols, cnt);
  k_scanA <<<NBLK_U, 256, 0, stream>>>(cnt, start, bsum);
  k_scanB <<<1, 512, 0, stream>>>(bsum, NBLK_U);
  k_scanC <<<NBLK_U, 256, 0, stream>>>(start, bsum);
  k_place <<<(E_N+255)/256, 256, 0, stream>>>(rows, cols, rats, start, fill, u_s, c_s);
  // weights + tiny GEMV
  k_ratpart <<<1, 320, 0, stream>>>(rating_feat, gv_w1, gv_b1, rating_part);
  k_prepw5  <<<80, 256, 0, stream>>>(gv_w1, att_w1, gv_w2, att_w2, w1t, u1t, w2t, a1t, a2t);
  // dense precompute (MFMA)
  k_rowgemm<false><<<(I_N+255)/256, 256, 0, stream>>>(item_feat, (const uint4*)w1t, nullptr,
                                                      (uint4*)item_part, I_N);
  k_rowgemm<true> <<<NBLK_U, 256, 0, stream>>>(user_feat, (const uint4*)u1t, att_b1,
                                               (uint4*)user_part, U_N);
  k_combo_mfma<<<NBLK_C, 256, 0, stream>>>((const uint4*)item_part, (const float4*)rating_part,
                                           (const uint4*)w2t, (const uint4*)a1t, gv_b2,
                                           (uint4*)xia_t, (uint4*)xa1_t);
  // per-edge logits (MFMA)
  k_edge_mfma<<<NBLK_E, 256, 0, stream>>>(u_s, c_s, (const uint4*)xa1_t, (const uint4*)user_part,
                                          (const uint4*)a2t, att_b2, att_w3, att_b3, wlog_s);
  // fused softmax + aggregate + output projection
  k_gather  <<<U_N/4, 256, 0, stream>>>(start, c_s, wlog_s, xia_t, w_w, w_b, out);
}

// Round 6
// 406.008 us; speedup vs baseline: 3.2198x; 1.2499x over previous
//
#include <hip/hip_runtime.h>
#include <hip/hip_bf16.h>

#define U_N 100000
#define I_N 50000
#define E_N 2000000
#define R_N 5
#define C_N (I_N*R_N)   // 250000 combos
#define NBLK_U 391      // ceil(100000/256); NBLK_U*256 = 100096
#define NBLK_E 7813     // ceil(2000000/256)
#define NBLK_C 1954     // ceil(250000/128)
#define NBUCK 782       // ceil(100000/128) user buckets
#define SUBB 8          // sub-buckets (one per XCD via blockIdx&7)
#define CAPB 512        // capacity per (bucket,sub); mean 320, >10 sigma headroom

typedef __hip_bfloat16 bf16_t;
typedef unsigned short u16;
typedef __attribute__((ext_vector_type(8))) short bf16x8;
typedef __attribute__((ext_vector_type(4))) float f32x4;

__device__ __forceinline__ float blo(unsigned u){ return __uint_as_float(u<<16); }
__device__ __forceinline__ float bhi(unsigned u){ return __uint_as_float(u & 0xffff0000u); }
__device__ __forceinline__ unsigned pkbf(float a, float b){
  __hip_bfloat162 t = __float22bfloat162_rn(float2{a,b});
  union { __hip_bfloat162 h; unsigned u; } cv; cv.h = t; return cv.u;
}
__device__ __forceinline__ u16 f2b(float v){
  union { __hip_bfloat16 h; u16 u; } cv; cv.h = __float2bfloat16(v); return cv.u;
}

// ---------------- CSR build: bucketed two-pass ----------------
__global__ __launch_bounds__(256) void k_zero_tails(int* tails){
  int i = blockIdx.x*256 + threadIdx.x;
  if(i < NBUCK*SUBB) tails[i] = 0;
}

// pass A: append (u,c) to bucket (u>>7), sub-bucket by blockIdx&7 (XCD-local appends)
__global__ __launch_bounds__(256) void k_binA(const int* __restrict__ rows, const int* __restrict__ cols,
                                              const int* __restrict__ rats,
                                              int* __restrict__ tails, int2* __restrict__ uc){
  int e = blockIdx.x*256 + threadIdx.x; if(e >= E_N) return;
  int u = cols[e];
  int c = rows[e]*5 + rats[e];
  int b = u >> 7;
  int sb = b*SUBB + (blockIdx.x & 7);
  int slot = atomicAdd(tails + sb, 1);
  if(slot < CAPB) uc[(size_t)sb*CAPB + slot] = make_int2(u, c);
}

// pass B1: per-bucket LDS histogram -> cnt (coalesced writes; replaces global atomic count)
__global__ __launch_bounds__(256) void k_binB1(const int* __restrict__ tails, const int2* __restrict__ uc,
                                               int* __restrict__ cnt){
  __shared__ int hist[128];
  int t = threadIdx.x, b = blockIdx.x;
  if(t < 128) hist[t] = 0;
  __syncthreads();
  for(int sub=0; sub<SUBB; ++sub){
    int sb = b*SUBB + sub;
    int n = tails[sb]; if(n > CAPB) n = CAPB;
    const int2* p = uc + (size_t)sb*CAPB;
    for(int j=t; j<n; j+=256) atomicAdd(&hist[p[j].x & 127], 1);
  }
  __syncthreads();
  if(t < 128) cnt[b*128 + t] = hist[t];   // b*128+t < 100096 == cnt size
}

__global__ __launch_bounds__(256) void k_scanA(const int* __restrict__ cnt, int* __restrict__ start,
                                               int* __restrict__ bsum){
  __shared__ int s[256];
  int t = threadIdx.x, i = blockIdx.x*256 + t;
  int v = (i < U_N) ? cnt[i] : 0;
  s[t] = v; __syncthreads();
  for(int off=1; off<256; off<<=1){
    int x = (t>=off) ? s[t-off] : 0;
    __syncthreads();
    s[t] += x;
    __syncthreads();
  }
  start[i] = s[t] - v;
  if(t == 255) bsum[blockIdx.x] = s[255];
}

__global__ void k_scanB(int* bsum, int n){
  __shared__ int s[512];
  int t = threadIdx.x;
  int v = (t < n) ? bsum[t] : 0;
  s[t] = v; __syncthreads();
  for(int off=1; off<512; off<<=1){
    int x = (t>=off) ? s[t-off] : 0;
    __syncthreads();
    s[t] += x;
    __syncthreads();
  }
  if(t < n) bsum[t] = s[t] - v;
}

__global__ __launch_bounds__(256) void k_scanC(int* start, const int* __restrict__ bsum){
  int i = blockIdx.x*256 + threadIdx.x;
  start[i] += bsum[blockIdx.x];
}

// pass B2: per-bucket placement; final windows (~20KB) are L2-resident -> no write amplification
__global__ __launch_bounds__(256) void k_binB2(const int* __restrict__ tails, const int2* __restrict__ uc,
                                               const int* __restrict__ start,
                                               int* __restrict__ u_s, int* __restrict__ c_s){
  __shared__ int fillb[128];
  __shared__ int startb[128];
  int t = threadIdx.x, b = blockIdx.x;
  if(t < 128){
    fillb[t] = 0;
    startb[t] = start[b*128 + t];   // max index 781*128+127 = 100095 < 100096
  }
  __syncthreads();
  for(int sub=0; sub<SUBB; ++sub){
    int sb = b*SUBB + sub;
    int n = tails[sb]; if(n > CAPB) n = CAPB;
    const int2* p = uc + (size_t)sb*CAPB;
    for(int j=t; j<n; j+=256){
      int2 e = p[j];
      int ul = e.x & 127;
      int off = atomicAdd(&fillb[ul], 1);
      int pos = startb[ul] + off;
      u_s[pos] = e.x;
      c_s[pos] = e.y;
    }
  }
}

// ---------------- tiny precompute ----------------
__global__ void k_ratpart(const float* __restrict__ rf, const float* __restrict__ w1,
                          const float* __restrict__ b1, float* __restrict__ out){
  int t = threadIdx.x; if(t >= R_N*64) return;
  int r = t>>6, d = t&63;
  float acc = b1[d];
  for(int k=0;k<64;k++) acc += rf[r*64 + k] * w1[(64+k)*64 + d];
  out[t] = acc;
}

__global__ __launch_bounds__(256) void k_prepw5(const float* __restrict__ w1, const float* __restrict__ a1,
                                                const float* __restrict__ w2, const float* __restrict__ a2,
                                                u16* w1t, u16* u1t, u16* w2t, u16* a1t, u16* a2t){
  int idx = (blockIdx.x & 15)*256 + threadIdx.x;
  int sec = blockIdx.x >> 4;
  int d = idx >> 6, k = idx & 63;
  const float* src; u16* dst; int ko = 0;
  switch(sec){
    case 0: src=w1; dst=w1t; break;
    case 1: src=a1; dst=u1t; ko=64; break;
    case 2: src=w2; dst=w2t; break;
    case 3: src=a1; dst=a1t; break;
    default: src=a2; dst=a2t; break;
  }
  dst[idx] = f2b(src[(size_t)(ko+k)*64 + d]);
}

// ---------------- MFMA row-GEMM: out[n][64](bf16) = in[n][64](f32) @ W (+bias) ----------------
template<bool BIAS>
__global__ __launch_bounds__(256) void k_rowgemm(const float4* __restrict__ in,
                                                 const uint4* __restrict__ wt,
                                                 const float* __restrict__ bias,
                                                 uint4* __restrict__ outp, int n){
  __shared__ uint4 A_u4[2048];
  __shared__ uint4 W_u4[512];
  __shared__ float bsh[64];
  u16* A16 = (u16*)A_u4;
  const int tid = threadIdx.x;
  for(int cid = tid; cid < 512; cid += 256){
    int dd = cid >> 3, ch = cid & 7;
    W_u4[dd*8 + (ch ^ (dd&7))] = wt[cid];
  }
  if(BIAS && tid < 64) bsh[tid] = bias[tid];
  const int base = blockIdx.x*256;
  const int ch = tid & 7;
#pragma unroll
  for(int it=0; it<8; ++it){
    int s = it*32 + (tid>>3);
    int r = base + s;
    uint4 o = {0,0,0,0};
    if(r < n){
      const float4* p = in + (size_t)r*16 + ch*2;
      float4 v0 = p[0], v1 = p[1];
      o.x = pkbf(v0.x, v0.y); o.y = pkbf(v0.z, v0.w);
      o.z = pkbf(v1.x, v1.y); o.w = pkbf(v1.z, v1.w);
    }
    A_u4[s*8 + (ch ^ (s&7))] = o;
  }
  __syncthreads();
  const int l = tid & 63, w = tid >> 6;
  const int lr = l & 15, g = l >> 4;
  bf16x8 bfr[4][2];
#pragma unroll
  for(int nt=0; nt<4; ++nt)
#pragma unroll
    for(int kk=0; kk<2; ++kk){
      int d = nt*16 + lr;
      bfr[nt][kk] = *(const bf16x8*)&W_u4[d*8 + ((kk*4+g) ^ (d&7))];
    }
  float bv[4];
#pragma unroll
  for(int nt=0; nt<4; ++nt) bv[nt] = BIAS ? bsh[nt*16 + lr] : 0.f;
#pragma unroll
  for(int t=0; t<4; ++t){
    int s = w*64 + t*16 + lr;
    bf16x8 af0 = *(const bf16x8*)&A_u4[s*8 + ((0*4+g) ^ (s&7))];
    bf16x8 af1 = *(const bf16x8*)&A_u4[s*8 + ((1*4+g) ^ (s&7))];
    f32x4 acc[4];
#pragma unroll
    for(int nt=0; nt<4; ++nt){
      f32x4 c0 = { bv[nt], bv[nt], bv[nt], bv[nt] };
      c0 = __builtin_amdgcn_mfma_f32_16x16x32_bf16(af0, bfr[nt][0], c0, 0, 0, 0);
      c0 = __builtin_amdgcn_mfma_f32_16x16x32_bf16(af1, bfr[nt][1], c0, 0, 0, 0);
      acc[nt] = c0;
    }
#pragma unroll
    for(int nt=0; nt<4; ++nt){
      int d = nt*16 + lr;
#pragma unroll
      for(int reg=0; reg<4; ++reg){
        int srow = w*64 + t*16 + g*4 + reg;
        A16[srow*64 + ((d>>3)^(srow&7))*8 + (d&7)] = f2b(acc[nt][reg]);
      }
    }
  }
#pragma unroll
  for(int it=0; it<8; ++it){
    int s = w*64 + it*8 + (l>>3);
    int c2 = l & 7;
    int r = base + s;
    if(r < n) outp[(size_t)r*8 + c2] = A_u4[s*8 + (c2 ^ (s&7))];
  }
}

// ---------------- combo: h1=relu(itemp+ratp); x_ia=relu(h1@W2+b2); xa1=x_ia@A1top ----------------
__global__ __launch_bounds__(256) void k_combo_mfma(const uint4* __restrict__ itemp,
                                                    const float4* __restrict__ ratp,
                                                    const uint4* __restrict__ w2t_g, const uint4* __restrict__ a1t_g,
                                                    const float* __restrict__ b2,
                                                    uint4* __restrict__ xia_o, uint4* __restrict__ xa1_o){
  __shared__ uint4 A_u4[1024];
  __shared__ uint4 X_u4[1024];
  __shared__ uint4 W2_u4[512];
  __shared__ uint4 A1_u4[512];
  __shared__ float4 rsh4[80];
  __shared__ float b2sh[64];
  u16* A16 = (u16*)A_u4;
  u16* X16 = (u16*)X_u4;
  const int tid = threadIdx.x;
  for(int cid = tid; cid < 512; cid += 256){
    int dd = cid >> 3, ch = cid & 7;
    W2_u4[dd*8 + (ch ^ (dd&7))] = w2t_g[cid];
    A1_u4[dd*8 + (ch ^ (dd&7))] = a1t_g[cid];
  }
  if(tid < 80) rsh4[tid] = ratp[tid];
  if(tid < 64) b2sh[tid] = b2[tid];
  __syncthreads();

  const int base = blockIdx.x*128;
  const int ch = tid & 7;
#pragma unroll
  for(int it=0; it<4; ++it){
    int s = it*32 + (tid>>3);
    int cidx = base + s;
    uint4 o = {0,0,0,0};
    if(cidx < C_N){
      int i = cidx/5, r = cidx - i*5;
      uint4 iv = itemp[(size_t)i*8 + ch];
      float4 r0 = rsh4[r*16 + ch*2], r1 = rsh4[r*16 + ch*2 + 1];
      o.x = pkbf(fmaxf(blo(iv.x)+r0.x,0.f), fmaxf(bhi(iv.x)+r0.y,0.f));
      o.y = pkbf(fmaxf(blo(iv.y)+r0.z,0.f), fmaxf(bhi(iv.y)+r0.w,0.f));
      o.z = pkbf(fmaxf(blo(iv.z)+r1.x,0.f), fmaxf(bhi(iv.z)+r1.y,0.f));
      o.w = pkbf(fmaxf(blo(iv.w)+r1.z,0.f), fmaxf(bhi(iv.w)+r1.w,0.f));
    }
    A_u4[s*8 + (ch ^ (s&7))] = o;
  }
  __syncthreads();

  const int l = tid & 63, w = tid >> 6;
  const int lr = l & 15, g = l >> 4;
  bf16x8 w2f[4][2], a1f[4][2];
#pragma unroll
  for(int nt=0; nt<4; ++nt)
#pragma unroll
    for(int kk=0; kk<2; ++kk){
      int d = nt*16 + lr;
      w2f[nt][kk] = *(const bf16x8*)&W2_u4[d*8 + ((kk*4+g) ^ (d&7))];
      a1f[nt][kk] = *(const bf16x8*)&A1_u4[d*8 + ((kk*4+g) ^ (d&7))];
    }
  float b2v[4];
#pragma unroll
  for(int nt=0; nt<4; ++nt) b2v[nt] = b2sh[nt*16 + lr];

#pragma unroll
  for(int t=0; t<2; ++t){
    int s = w*32 + t*16 + lr;
    bf16x8 af0 = *(const bf16x8*)&A_u4[s*8 + ((0*4+g) ^ (s&7))];
    bf16x8 af1 = *(const bf16x8*)&A_u4[s*8 + ((1*4+g) ^ (s&7))];
#pragma unroll
    for(int nt=0; nt<4; ++nt){
      f32x4 c0 = { b2v[nt], b2v[nt], b2v[nt], b2v[nt] };
      c0 = __builtin_amdgcn_mfma_f32_16x16x32_bf16(af0, w2f[nt][0], c0, 0, 0, 0);
      c0 = __builtin_amdgcn_mfma_f32_16x16x32_bf16(af1, w2f[nt][1], c0, 0, 0, 0);
      int d = nt*16 + lr;
#pragma unroll
      for(int reg=0; reg<4; ++reg){
        int srow = w*32 + t*16 + g*4 + reg;
        X16[srow*64 + ((d>>3)^(srow&7))*8 + (d&7)] = f2b(fmaxf(c0[reg], 0.f));
      }
    }
    bf16x8 xf0 = *(const bf16x8*)&X_u4[s*8 + ((0*4+g) ^ (s&7))];
    bf16x8 xf1 = *(const bf16x8*)&X_u4[s*8 + ((1*4+g) ^ (s&7))];
#pragma unroll
    for(int nt=0; nt<4; ++nt){
      f32x4 c0 = { 0.f, 0.f, 0.f, 0.f };
      c0 = __builtin_amdgcn_mfma_f32_16x16x32_bf16(xf0, a1f[nt][0], c0, 0, 0, 0);
      c0 = __builtin_amdgcn_mfma_f32_16x16x32_bf16(xf1, a1f[nt][1], c0, 0, 0, 0);
      int d = nt*16 + lr;
#pragma unroll
      for(int reg=0; reg<4; ++reg){
        int srow = w*32 + t*16 + g*4 + reg;
        A16[srow*64 + ((d>>3)^(srow&7))*8 + (d&7)] = f2b(c0[reg]);
      }
    }
  }
#pragma unroll
  for(int it=0; it<4; ++it){
    int s = w*32 + it*8 + (l>>3);
    int c2 = l & 7;
    int r = base + s;
    if(r < C_N){
      xia_o[(size_t)r*8 + c2] = X_u4[s*8 + (c2 ^ (s&7))];
      xa1_o[(size_t)r*8 + c2] = A_u4[s*8 + (c2 ^ (s&7))];
    }
  }
}

// ---------------- MFMA edge-logit kernel ----------------
__global__ __launch_bounds__(256) void k_edge_mfma(const int* __restrict__ u_s, const int* __restrict__ c_s,
                                                   const uint4* __restrict__ xa1p, const uint4* __restrict__ userp,
                                                   const uint4* __restrict__ a2t_g,
                                                   const float* __restrict__ a2b,
                                                   const float* __restrict__ a3w, const float* __restrict__ a3b,
                                                   float* __restrict__ wlog){
  __shared__ uint4 A_u4[2048];
  __shared__ uint4 W_u4[512];
  __shared__ float b2s[64];
  __shared__ float a3s[64];
  const int tid = threadIdx.x;
  for(int cid = tid; cid < 512; cid += 256){
    int d = cid >> 3, ch = cid & 7;
    W_u4[d*8 + (ch ^ (d&7))] = a2t_g[cid];
  }
  if(tid < 64){ b2s[tid] = a2b[tid]; a3s[tid] = a3w[tid]; }
  const int base = blockIdx.x*256;
  const int ch = tid & 7;
#pragma unroll
  for(int it=0; it<8; ++it){
    int s = it*32 + (tid>>3);
    int e = base + s;
    uint4 xv = {0,0,0,0}, uv = {0,0,0,0};
    if(e < E_N){
      int c = c_s[e], u = u_s[e];
      xv = xa1p[(size_t)c*8 + ch];
      uv = userp[(size_t)u*8 + ch];
    }
    uint4 o;
    o.x = pkbf(fmaxf(blo(xv.x)+blo(uv.x),0.f), fmaxf(bhi(xv.x)+bhi(uv.x),0.f));
    o.y = pkbf(fmaxf(blo(xv.y)+blo(uv.y),0.f), fmaxf(bhi(xv.y)+bhi(uv.y),0.f));
    o.z = pkbf(fmaxf(blo(xv.z)+blo(uv.z),0.f), fmaxf(bhi(xv.z)+bhi(uv.z),0.f));
    o.w = pkbf(fmaxf(blo(xv.w)+blo(uv.w),0.f), fmaxf(bhi(xv.w)+bhi(uv.w),0.f));
    A_u4[s*8 + (ch ^ (s&7))] = o;
  }
  __syncthreads();
  const int l = tid & 63, w = tid >> 6;
  const int lr = l & 15;
  const int g  = l >> 4;
  bf16x8 bf[4][2];
#pragma unroll
  for(int nt=0; nt<4; ++nt)
#pragma unroll
    for(int kk=0; kk<2; ++kk){
      int d = nt*16 + lr;
      bf[nt][kk] = *(const bf16x8*)&W_u4[d*8 + ((kk*4 + g) ^ (d&7))];
    }
  float b2v[4], a3v[4];
#pragma unroll
  for(int nt=0; nt<4; ++nt){ b2v[nt] = b2s[nt*16 + lr]; a3v[nt] = a3s[nt*16 + lr]; }
  const float a3b0 = a3b[0];
#pragma unroll
  for(int t=0; t<4; ++t){
    int s = w*64 + t*16 + lr;
    bf16x8 af0 = *(const bf16x8*)&A_u4[s*8 + ((0*4 + g) ^ (s&7))];
    bf16x8 af1 = *(const bf16x8*)&A_u4[s*8 + ((1*4 + g) ^ (s&7))];
    f32x4 acc[4];
#pragma unroll
    for(int nt=0; nt<4; ++nt){
      f32x4 c0 = { b2v[nt], b2v[nt], b2v[nt], b2v[nt] };
      c0 = __builtin_amdgcn_mfma_f32_16x16x32_bf16(af0, bf[nt][0], c0, 0, 0, 0);
      c0 = __builtin_amdgcn_mfma_f32_16x16x32_bf16(af1, bf[nt][1], c0, 0, 0, 0);
      acc[nt] = c0;
    }
    float s0=0.f, s1=0.f, s2=0.f, s3=0.f;
#pragma unroll
    for(int nt=0; nt<4; ++nt){
      s0 += fmaxf(acc[nt][0], 0.f) * a3v[nt];
      s1 += fmaxf(acc[nt][1], 0.f) * a3v[nt];
      s2 += fmaxf(acc[nt][2], 0.f) * a3v[nt];
      s3 += fmaxf(acc[nt][3], 0.f) * a3v[nt];
    }
#pragma unroll
    for(int mask=1; mask<16; mask<<=1){
      s0 += __shfl_xor(s0, mask);
      s1 += __shfl_xor(s1, mask);
      s2 += __shfl_xor(s2, mask);
      s3 += __shfl_xor(s3, mask);
    }
    if(lr == 0){
      int e0 = base + w*64 + t*16 + g*4;
      if(e0+0 < E_N) wlog[e0+0] = s0 + a3b0;
      if(e0+1 < E_N) wlog[e0+1] = s1 + a3b0;
      if(e0+2 < E_N) wlog[e0+2] = s2 + a3b0;
      if(e0+3 < E_N) wlog[e0+3] = s3 + a3b0;
    }
  }
}

// ---------------- fused softmax + aggregate + output projection ----------------
__global__ __launch_bounds__(256) void k_gather(const int* __restrict__ start, const int* __restrict__ c_s,
                                                const float* __restrict__ wlog,
                                                const bf16_t* __restrict__ xia,
                                                const float* __restrict__ ww, const float* __restrict__ wb,
                                                float* __restrict__ out){
  __shared__ float Ws[4096];
  __shared__ float bsh[64];
  __shared__ float hsh[4][64];
  for(int idx=threadIdx.x; idx<4096; idx+=256) Ws[idx] = ww[idx];
  if(threadIdx.x < 64) bsh[threadIdx.x] = wb[threadIdx.x];
  __syncthreads();
  int w = threadIdx.x >> 6, lane = threadIdx.x & 63;
  int u = blockIdx.x*4 + w;
  int s0 = start[u], n = start[u+1] - s0;
  int nq = (n + 63) >> 6;
  float tq[4]; int cq[4];
  float m = -1e30f;
  for(int q=0; q<nq; ++q){
    int j = q*64 + lane;
    float t = (j<n) ? wlog[s0+j] : -1e30f;
    int c   = (j<n) ? c_s[s0+j] : 0;
    if(q<4){ tq[q]=t; cq[q]=c; }
    m = fmaxf(m, t);
  }
#pragma unroll
  for(int off=32; off>=1; off>>=1) m = fmaxf(m, __shfl_xor(m, off));
  float ssum = 0.f;
  for(int q=0; q<nq; ++q){
    int j = q*64 + lane;
    float t = (q<4) ? tq[q] : ((j<n) ? wlog[s0+j] : -1e30f);
    float e = (j<n) ? __expf(t - m) : 0.f;
    if(q<4) tq[q] = e;
    ssum += e;
  }
#pragma unroll
  for(int off=32; off>=1; off>>=1) ssum += __shfl_xor(ssum, off);
  float inv = (n>0) ? (1.f/ssum) : 0.f;
#pragma unroll
  for(int q=0; q<4; ++q) tq[q] *= inv;
  float acc = 0.f;
  for(int q=0; q<nq; ++q){
    float ev; int cv_;
    if(q<4){ ev = tq[q]; cv_ = cq[q]; }
    else {
      int j = q*64 + lane;
      float t = (j<n) ? wlog[s0+j] : -1e30f;
      cv_ = (j<n) ? c_s[s0+j] : 0;
      ev = (j<n) ? __expf(t - m)*inv : 0.f;
    }
    int lim = n - q*64; if(lim > 64) lim = 64;
    int ll = 0;
    for(; ll+4 <= lim; ll += 4){
      int   c0=__shfl(cv_,ll),  c1=__shfl(cv_,ll+1), c2=__shfl(cv_,ll+2), c3=__shfl(cv_,ll+3);
      float v0=__shfl(ev,ll),   v1=__shfl(ev,ll+1),  v2=__shfl(ev,ll+2),  v3=__shfl(ev,ll+3);
      float x0 = __bfloat162float(xia[(size_t)c0*64 + lane]);
      float x1 = __bfloat162float(xia[(size_t)c1*64 + lane]);
      float x2 = __bfloat162float(xia[(size_t)c2*64 + lane]);
      float x3 = __bfloat162float(xia[(size_t)c3*64 + lane]);
      acc = fmaf(x0, v0, acc); acc = fmaf(x1, v1, acc);
      acc = fmaf(x2, v2, acc); acc = fmaf(x3, v3, acc);
    }
    for(; ll<lim; ++ll){
      float v = __shfl(ev, ll); int c = __shfl(cv_, ll);
      acc = fmaf(__bfloat162float(xia[(size_t)c*64 + lane]), v, acc);
    }
  }
  hsh[w][lane] = acc;
  const float* hp = hsh[w];
  float o = bsh[lane];
  for(int k=0; k<64; ++k) o = fmaf(hp[k], Ws[k*64 + lane], o);
  out[(size_t)u*64 + lane] = o;
}

extern "C" void kernel_launch(void* const* d_in, const int* in_sizes, int n_in,
                              void* d_out, int out_size, void* d_ws, size_t ws_size,
                              hipStream_t stream){
  (void)in_sizes; (void)n_in; (void)out_size; (void)ws_size;
  const float4* user_feat  = (const float4*)d_in[0];
  const float4* item_feat  = (const float4*)d_in[1];
  const float*  rating_feat= (const float*)d_in[2];
  const int*    rows       = (const int*)d_in[3];
  const int*    cols       = (const int*)d_in[4];
  const int*    rats       = (const int*)d_in[5];
  const float* gv_w1 = (const float*)d_in[6];
  const float* gv_b1 = (const float*)d_in[7];
  const float* gv_w2 = (const float*)d_in[8];
  const float* gv_b2 = (const float*)d_in[9];
  const float* att_w1= (const float*)d_in[10];
  const float* att_b1= (const float*)d_in[11];
  const float* att_w2= (const float*)d_in[12];
  const float* att_b2= (const float*)d_in[13];
  const float* att_w3= (const float*)d_in[14];
  const float* att_b3= (const float*)d_in[15];
  const float* w_w   = (const float*)d_in[16];
  const float* w_b   = (const float*)d_in[17];
  float* out = (float*)d_out;

  char* ws = (char*)d_ws; size_t off = 0;
  auto take = [&](size_t b)->char*{ char* p = ws + off; off = (off + b + 255) & ~(size_t)255; return p; };
  bf16_t* item_part  = (bf16_t*)take((size_t)I_N*64*2);       // 6.4 MB
  bf16_t* user_part  = (bf16_t*)take((size_t)U_N*64*2);       // 12.8 MB
  float*  rating_part= (float*) take((size_t)R_N*64*4);
  bf16_t* xia_t      = (bf16_t*)take((size_t)C_N*64*2);       // 32 MB
  bf16_t* xa1_t      = (bf16_t*)take((size_t)C_N*64*2);       // 32 MB
  float*  wlog_s     = (float*) take((size_t)E_N*4);          // 8 MB
  int*    c_s        = (int*)   take((size_t)E_N*4);          // 8 MB
  int*    u_s        = (int*)   take((size_t)E_N*4);          // 8 MB
  int2*   uc         = (int2*)  take((size_t)NBUCK*SUBB*CAPB*8); // 25.6 MB
  int*    tails      = (int*)   take((size_t)NBUCK*SUBB*4);
  int*    cnt        = (int*)   take((size_t)(NBLK_U*256)*4);
  int*    start      = (int*)   take((size_t)(NBLK_U*256)*4);
  int*    bsum       = (int*)   take((size_t)512*4);
  u16*    w1t        = (u16*)   take((size_t)4096*2);
  u16*    u1t        = (u16*)   take((size_t)4096*2);
  u16*    w2t        = (u16*)   take((size_t)4096*2);
  u16*    a1t        = (u16*)   take((size_t)4096*2);
  u16*    a2t        = (u16*)   take((size_t)4096*2);

  // CSR build (bucketed)
  k_zero_tails<<<(NBUCK*SUBB+255)/256, 256, 0, stream>>>(tails);
  k_binA <<<NBLK_E, 256, 0, stream>>>(rows, cols, rats, tails, uc);
  k_binB1<<<NBUCK, 256, 0, stream>>>(tails, uc, cnt);
  k_scanA<<<NBLK_U, 256, 0, stream>>>(cnt, start, bsum);
  k_scanB<<<1, 512, 0, stream>>>(bsum, NBLK_U);
  k_scanC<<<NBLK_U, 256, 0, stream>>>(start, bsum);
  k_binB2<<<NBUCK, 256, 0, stream>>>(tails, uc, start, u_s, c_s);
  // weights + tiny GEMV
  k_ratpart <<<1, 320, 0, stream>>>(rating_feat, gv_w1, gv_b1, rating_part);
  k_prepw5  <<<80, 256, 0, stream>>>(gv_w1, att_w1, gv_w2, att_w2, w1t, u1t, w2t, a1t, a2t);
  // dense precompute (MFMA)
  k_rowgemm<false><<<(I_N+255)/256, 256, 0, stream>>>(item_feat, (const uint4*)w1t, nullptr,
                                                      (uint4*)item_part, I_N);
  k_rowgemm<true> <<<NBLK_U, 256, 0, stream>>>(user_feat, (const uint4*)u1t, att_b1,
                                               (uint4*)user_part, U_N);
  k_combo_mfma<<<NBLK_C, 256, 0, stream>>>((const uint4*)item_part, (const float4*)rating_part,
                                           (const uint4*)w2t, (const uint4*)a1t, gv_b2,
                                           (uint4*)xia_t, (uint4*)xa1_t);
  // per-edge logits (MFMA)
  k_edge_mfma<<<NBLK_E, 256, 0, stream>>>(u_s, c_s, (const uint4*)xa1_t, (const uint4*)user_part,
                                          (const uint4*)a2t, att_b2, att_w3, att_b3, wlog_s);
  // fused softmax + aggregate + output projection
  k_gather  <<<U_N/4, 256, 0, stream>>>(start, c_s, wlog_s, xia_t, w_w, w_b, out);
}